// Round 1
// baseline (531.122 us; speedup 1.0000x reference)
//
#include <hip/hip_runtime.h>
#include <hip/hip_bf16.h>

typedef __bf16  bf16x8 __attribute__((ext_vector_type(8)));
typedef float   f32x4  __attribute__((ext_vector_type(4)));
typedef short   s16x8  __attribute__((ext_vector_type(8)));

typedef const __attribute__((address_space(1))) void g_void;
typedef __attribute__((address_space(3))) void l_void;

__device__ __forceinline__ short f2b(float x) {
    __hip_bfloat16 h = __float2bfloat16(x);
    return __builtin_bit_cast(short, h);
}

// pack two floats to bf16 pair in one int (lo | hi<<16)
__device__ __forceinline__ int pk2(float lo, float hi) {
    return (int)(unsigned short)f2b(lo) | ((int)f2b(hi) << 16);
}

// fast GELU: tanh form via hardware exp2. gelu(v) = v*t/(t+1),
// t = exp2(K1*(v + 0.044715 v^3)), K1 = 2*log2(e)*0.7978845608.
__device__ __forceinline__ float fast_gelu(float v) {
    const float a = fminf(2.3022082f * (v + 0.044715f * v * v * v), 126.0f);
    const float t = exp2f(a);
    return v * t / (t + 1.0f);
}

__device__ __forceinline__ f32x4 mfma16(s16x8 a, s16x8 b, f32x4 c) {
    return __builtin_amdgcn_mfma_f32_16x16x32_bf16(
        __builtin_bit_cast(bf16x8, a), __builtin_bit_cast(bf16x8, b), c, 0, 0, 0);
}

// ---------------- transpose + fp32 -> bf16 :  src [R,C] f32 -> dst [C,R] bf16
__global__ __launch_bounds__(256) void transpose_bf16(
    const float* __restrict__ src, short* __restrict__ dst, int R, int C) {
    __shared__ float tile[32][33];
    src += (size_t)blockIdx.z * R * C;
    dst += (size_t)blockIdx.z * R * C;
    const int c0 = blockIdx.x * 32, r0 = blockIdx.y * 32;
    const int tx = threadIdx.x & 31, ty = threadIdx.x >> 5;
#pragma unroll
    for (int i = 0; i < 32; i += 8)
        tile[ty + i][tx] = src[(size_t)(r0 + ty + i) * C + c0 + tx];
    __syncthreads();
#pragma unroll
    for (int i = 0; i < 32; i += 8)
        dst[(size_t)(c0 + ty + i) * R + r0 + tx] = f2b(tile[tx][ty + i]);
}

// ---------------- concat q/k/v bias into [3072] f32
__global__ __launch_bounds__(256) void concat_bias(
    const float* __restrict__ bq, const float* __restrict__ bk,
    const float* __restrict__ bv, float* __restrict__ o) {
    int i = blockIdx.x * 256 + threadIdx.x;
    if (i < 1024)      o[i] = bq[i];
    else if (i < 2048) o[i] = bk[i - 1024];
    else if (i < 3072) o[i] = bv[i - 2048];
}

// ---------------- LayerNorm (D=1024) f32 in -> bf16 out. 1 block/row, 256 thr
__global__ __launch_bounds__(256) void ln_bf16(
    const float* __restrict__ x, const float* __restrict__ gamma,
    const float* __restrict__ beta, short* __restrict__ out) {
    __shared__ float red[8];
    const int row = blockIdx.x, tid = threadIdx.x;
    const float4 v = *(const float4*)(x + (size_t)row * 1024 + tid * 4);
    float s = v.x + v.y + v.z + v.w;
    float q = v.x * v.x + v.y * v.y + v.z * v.z + v.w * v.w;
#pragma unroll
    for (int off = 32; off > 0; off >>= 1) {
        s += __shfl_xor(s, off);
        q += __shfl_xor(q, off);
    }
    if ((tid & 63) == 0) { red[(tid >> 6) * 2] = s; red[(tid >> 6) * 2 + 1] = q; }
    __syncthreads();
    s = red[0] + red[2] + red[4] + red[6];
    q = red[1] + red[3] + red[5] + red[7];
    const float mu = s * (1.0f / 1024.0f);
    const float var = q * (1.0f / 1024.0f) - mu * mu;
    const float rs = rsqrtf(var + 1e-5f);
    const float4 g  = *(const float4*)(gamma + tid * 4);
    const float4 bt = *(const float4*)(beta + tid * 4);
    short4 o;
    o.x = f2b((v.x - mu) * rs * g.x + bt.x);
    o.y = f2b((v.y - mu) * rs * g.y + bt.y);
    o.z = f2b((v.z - mu) * rs * g.z + bt.z);
    o.w = f2b((v.w - mu) * rs * g.w + bt.w);
    *(short4*)(out + (size_t)row * 1024 + tid * 4) = o;
}

// ---------------- OLD bf16 MFMA GEMM (128x128, 2-barrier). Kept for the
// narrow-N GEMMs (Wo, MLP2: N=1024 -> only 128 blocks at 256^2 tile).
// MODE 1: out f32 = acc + bias[col] + resid[row*N+col]
template <int MODE, int SWZ>
__global__ __launch_bounds__(512) void gemm_bf16(
    const short* __restrict__ A, const short* __restrict__ Bt,
    const float* __restrict__ bias, const float* __restrict__ resid,
    float* __restrict__ outf, short* __restrict__ outb, short* __restrict__ vt,
    int M, int N, int K) {
    __shared__ __align__(16) short As[2 * 128 * 32];
    __shared__ __align__(16) short Bs[2 * 128 * 32];

    const int tid = threadIdx.x;
    const int wave = tid >> 6, lane = tid & 63;
    const int l16 = lane & 15, quad = lane >> 4;
    const int wm = wave & 3, wn = wave >> 2;   // 4 row-strips x 2 col-strips
    const int gx = gridDim.x;
    const int g = blockIdx.y * gx + blockIdx.x;
    const int xcd = g & 7, s = g >> 3;
    int m0, n0;
    if (SWZ == 0) {                            // N-band (requires gx % 8 == 0)
        const int nband = gx >> 3;
        const int sm = s / nband;
        const int sn = s - sm * nband;
        m0 = sm * 128;
        n0 = (xcd * nband + sn) * 128;
    } else {                                   // M-band (requires gy % 8 == 0)
        const int mband = gridDim.y >> 3;
        const int sm = s / gx;
        m0 = (xcd * mband + sm) * 128;
        n0 = (s - sm * gx) * 128;
    }
    const int lrow = lane >> 2;        // 0..15
    const int lcol = (lane & 3) * 8;   // 16B chunk within a 32-elem panel row

    f32x4 acc[2][4] = {};

    for (int kk = 0; kk < K; kk += 64) {
#pragma unroll
        for (int p = 0; p < 2; ++p) {        // 32-K panel
            const int r = wave * 16 + lrow;  // 8 waves x 16 rows = 128
            const short* ga = A + (size_t)(m0 + r) * K + kk + p * 32 + lcol;
            short* la = &As[p * 4096 + wave * 512];
            __builtin_amdgcn_global_load_lds((g_void*)ga, (l_void*)la, 16, 0, 0);
            const short* gb = Bt + (size_t)(n0 + r) * K + kk + p * 32 + lcol;
            short* lb = &Bs[p * 4096 + wave * 512];
            __builtin_amdgcn_global_load_lds((g_void*)gb, (l_void*)lb, 16, 0, 0);
        }
        __syncthreads();
#pragma unroll
        for (int p = 0; p < 2; ++p) {
            s16x8 a[2], b[4];
#pragma unroll
            for (int t = 0; t < 2; ++t)
                a[t] = *(const s16x8*)&As[p * 4096 + (wm * 32 + t * 16 + l16) * 32 + quad * 8];
#pragma unroll
            for (int t = 0; t < 4; ++t)
                b[t] = *(const s16x8*)&Bs[p * 4096 + (wn * 64 + t * 16 + l16) * 32 + quad * 8];
#pragma unroll
            for (int mt = 0; mt < 2; ++mt)
#pragma unroll
                for (int nt = 0; nt < 4; ++nt)
                    acc[mt][nt] = mfma16(a[mt], b[nt], acc[mt][nt]);
        }
        __syncthreads();
    }

#pragma unroll
    for (int mt = 0; mt < 2; ++mt) {
#pragma unroll
        for (int nt = 0; nt < 4; ++nt) {
            const int row = m0 + wm * 32 + mt * 16 + quad * 4;   // + r
            const int col = n0 + wn * 64 + nt * 16 + l16;
            const float bc = bias[col];
            float v[4];
#pragma unroll
            for (int r = 0; r < 4; ++r) v[r] = acc[mt][nt][r] + bc;

            if (MODE == 1) {
#pragma unroll
                for (int r = 0; r < 4; ++r) {
                    const size_t rr = (size_t)(row + r);
                    outf[rr * N + col] = v[r] + resid[rr * N + col];
                }
            } else {
#pragma unroll
                for (int r = 0; r < 4; ++r)
                    outb[(size_t)(row + r) * N + col] = f2b(fast_gelu(v[r]));
            }
        }
    }
}

// ======================= 256x256 8-phase GEMM (T2+T3+T4+T5) ==================
// BM=BN=256, BK=64, 512 threads = 8 waves (2M x 4N), per-wave 128x64 output.
// LDS: A,B each 2 bufs x 2 halves x (128x64) bf16 = 64 KiB -> 128 KiB total.
// st_16x32 swizzle: 16x32-bf16 subtiles (1024B contiguous), byte ^= ((b>>9)&1)<<5.
// global_load_lds writes LINEAR chunks; the global SOURCE address is
// inverse-swizzled per-thread so reads use the swizzled address (rule #21).
// Per iteration = 2 K-tiles = 8 phases; each phase: {ds_read subtile | stage
// one half-tile | barrier | setprio(1) 16xMFMA setprio(0) | barrier}.
// vmcnt(4) ONLY at phases 4 and 8 (2 stages = 4 loads stay in flight).
// Stage/dead schedule (iter t: P1-4 compute buf0=K(2t), P5-8 buf1=K(2t+1)):
//   P1: buf1.Ah0<-K(2t+1)  P2: buf1.Ah1   (dead since prev P7)
//   P3: buf0.Bh0<-K(2t+2)  P4: buf0.Bh1   (dead after P2)
//   P5: buf0.Ah0<-K(2t+2)  P6: buf0.Ah1   (dead after P3)
//   P7: buf1.Bh0<-K(2t+3)  P8: buf1.Bh1   (dead after P6)
// P4's vmcnt(4) completes ...,prevP7,prevP8,S1,S2 -> all of buf1 ready for P5.
// P8's vmcnt(4) completes S3..S6 -> all of buf0 ready for next P1.

#define MM(MH, NH, AF, BB)                                                   \
    _Pragma("unroll") for (int p = 0; p < 2; ++p)                            \
        _Pragma("unroll") for (int ii = 0; ii < 4; ++ii)                     \
            _Pragma("unroll") for (int jj = 0; jj < 2; ++jj)                 \
                acc[(MH) * 4 + ii][(NH) * 2 + jj] =                          \
                    mfma16(AF[ii][p], BB[jj][p],                             \
                           acc[(MH) * 4 + ii][(NH) * 2 + jj]);

#define PH_MID                                                               \
    __builtin_amdgcn_s_barrier();                                            \
    __builtin_amdgcn_s_setprio(1);

#define PH_END                                                               \
    __builtin_amdgcn_s_setprio(0);                                           \
    __builtin_amdgcn_sched_barrier(0);                                       \
    __builtin_amdgcn_s_barrier();                                            \
    __builtin_amdgcn_sched_barrier(0);

// 4 phases of one K-tile in buffer BUF; S1..S4 = per-phase stage statements.
// WAIT4 true on the K-tile whose 4th phase is P4/P8 (both, here).
#define KTILE(BUF, S1, S2, S3, S4)                                           \
    {                                                                        \
        s16x8 af[4][2], bl[2][2], bh[2][2];                                  \
        /* P1: quadrant (0,0) */                                             \
        _Pragma("unroll") for (int ii = 0; ii < 4; ++ii)                     \
            _Pragma("unroll") for (int p = 0; p < 2; ++p)                    \
                af[ii][p] = LDA(BUF, ii, p);                                 \
        _Pragma("unroll") for (int jj = 0; jj < 2; ++jj)                     \
            _Pragma("unroll") for (int p = 0; p < 2; ++p)                    \
                bl[jj][p] = LDB(BUF, jj, p);                                 \
        S1;                                                                  \
        PH_MID;                                                              \
        MM(0, 0, af, bl);                                                    \
        PH_END;                                                              \
        /* P2: quadrant (0,1) */                                             \
        _Pragma("unroll") for (int jj = 0; jj < 2; ++jj)                     \
            _Pragma("unroll") for (int p = 0; p < 2; ++p)                    \
                bh[jj][p] = LDB(BUF, 2 + jj, p);                             \
        S2;                                                                  \
        PH_MID;                                                              \
        MM(0, 1, af, bh);                                                    \
        PH_END;                                                              \
        /* P3: quadrant (1,1) */                                             \
        _Pragma("unroll") for (int ii = 0; ii < 4; ++ii)                     \
            _Pragma("unroll") for (int p = 0; p < 2; ++p)                    \
                af[ii][p] = LDA(BUF, 4 + ii, p);                             \
        S3;                                                                  \
        PH_MID;                                                              \
        MM(1, 1, af, bh);                                                    \
        PH_END;                                                              \
        /* P4: quadrant (1,0), counted vmcnt */                              \
        S4;                                                                  \
        asm volatile("s_waitcnt vmcnt(4)" ::: "memory");                     \
        PH_MID;                                                              \
        MM(1, 0, af, bl);                                                    \
        PH_END;                                                              \
    }

// MODE 0: QKV scatter (Q pre-scaled, K -> [2][B,H,S,HD], V -> vt [B,H,HD,S])
// MODE 1: out f32 = acc + bias[col] + resid   MODE 2: out bf16 = gelu(acc+b)
template <int MODE>
__global__ __launch_bounds__(512, 2) void gemm256(
    const short* __restrict__ A, const short* __restrict__ Bt,
    const float* __restrict__ bias, const float* __restrict__ resid,
    float* __restrict__ outf, short* __restrict__ outb, short* __restrict__ vt,
    int M, int N, int K) {
    __shared__ __align__(16) short As[32768];   // 2 bufs x 2 halves x 8192
    __shared__ __align__(16) short Bs[32768];

    const int tid = threadIdx.x;
    const int wave = tid >> 6, lane = tid & 63;
    const int l16 = lane & 15, quad = lane >> 4;
    const int wm = wave >> 2, wn = wave & 3;    // 2 x 4 wave grid

    // XCD-chunked bijective swizzle (gridDim.x % 8 == 0), m-fastest order:
    // each XCD sweeps full m-columns of one n-band -> B-slice L2-resident.
    const int nwg = gridDim.x;
    const int g = blockIdx.x;
    const int wgid = (g & 7) * (nwg >> 3) + (g >> 3);
    const int mtiles = M >> 8;
    const int m0 = (wgid % mtiles) << 8;
    const int n0 = (wgid / mtiles) << 8;

    // ---- read-side swizzled offsets (in shorts)
    // lin = (sr*2+p)*512 + l16*32 + quad*8 ; swizzle flips short-bit4 (32B)
    // by short-bit8 (= l16>>3).
    const int rc = l16 * 32 + ((quad * 8) ^ ((l16 >> 3) << 4));
    const int a_rd = wm * 8192 + rc;                    // + (i*2+p)*512
    const int b_rd = (wn >> 1) * 8192 + (wn & 1) * 4096 + rc;

    auto LDA = [&](int buf, int i, int p) {
        return *(const s16x8*)&As[buf * 16384 + a_rd + (i * 2 + p) * 512];
    };
    auto LDB = [&](int buf, int j, int p) {
        return *(const s16x8*)&Bs[buf * 16384 + b_rd + (j * 2 + p) * 512];
    };

    // ---- stage-side inverse mapping: linear LDS chunk s=c*16 holds element
    // (r, col): lin = s ^ (((s>>9)&1)<<5); st=lin>>10; r=(st>>1)*16+((lin>>6)&15);
    // col = (st&1)*32 + ((lin&63)>>1).
    int r0, c0, r1, c1;
    {
        int s = tid * 16;
        int lin = s ^ (((s >> 9) & 1) << 5);
        r0 = ((lin >> 11) << 4) + ((lin >> 6) & 15);
        c0 = (((lin >> 10) & 1) << 5) + ((lin & 63) >> 1);
        s = (tid + 512) * 16;
        lin = s ^ (((s >> 9) & 1) << 5);
        r1 = ((lin >> 11) << 4) + ((lin >> 6) & 15);
        c1 = (((lin >> 10) & 1) << 5) + ((lin & 63) >> 1);
    }

    const short* gA = A + (size_t)m0 * K;
    const short* gB = Bt + (size_t)n0 * K;

    auto STAGE = [&](const short* gbase, int half, int kk, short* lds) {
        const short* s0 = gbase + (size_t)(half * 128 + r0) * K + kk + c0;
        const short* s1 = gbase + (size_t)(half * 128 + r1) * K + kk + c1;
        short* d0 = lds + half * 8192 + wave * 512;
        short* d1 = lds + half * 8192 + 4096 + wave * 512;
        __builtin_amdgcn_global_load_lds((g_void*)s0, (l_void*)d0, 16, 0, 0);
        __builtin_amdgcn_global_load_lds((g_void*)s1, (l_void*)d1, 16, 0, 0);
    };

    f32x4 acc[8][4] = {};

    // prologue: buf0 fully, buf1.B halves (buf1.A staged in-loop at P1/P2)
    STAGE(gA, 0, 0, As);
    STAGE(gA, 1, 0, As);
    STAGE(gB, 0, 0, Bs);
    STAGE(gB, 1, 0, Bs);
    STAGE(gB, 0, 64, Bs + 16384);
    STAGE(gB, 1, 64, Bs + 16384);
    asm volatile("s_waitcnt vmcnt(4)" ::: "memory");   // buf0 complete
    __builtin_amdgcn_s_barrier();
    __builtin_amdgcn_sched_barrier(0);

    const int NI = K >> 7;                              // 2 K-tiles / iter
    for (int it = 0; it < NI; ++it) {
        const int kA1 = (2 * it + 1) * 64;              // buf1 A data
        int kn0 = (2 * it + 2) * 64;                    // next buf0 data
        if (kn0 > K - 64) kn0 = K - 64;                 // clamp (unused dup)
        int kn1 = (2 * it + 3) * 64;                    // next buf1 data
        if (kn1 > K - 64) kn1 = K - 64;

        KTILE(0,
              STAGE(gA, 0, kA1, As + 16384),
              STAGE(gA, 1, kA1, As + 16384),
              STAGE(gB, 0, kn0, Bs),
              STAGE(gB, 1, kn0, Bs));
        KTILE(1,
              STAGE(gA, 0, kn0, As),
              STAGE(gA, 1, kn0, As),
              STAGE(gB, 0, kn1, Bs + 16384),
              STAGE(gB, 1, kn1, Bs + 16384));
    }

    // ---- epilogue
#pragma unroll
    for (int i = 0; i < 8; ++i) {
#pragma unroll
        for (int j = 0; j < 4; ++j) {
            const int row = m0 + wm * 128 + i * 16 + quad * 4;   // + r
            const int col = n0 + wn * 64 + j * 16 + l16;
            const float bc = bias[col];
            float v[4];
#pragma unroll
            for (int r = 0; r < 4; ++r) v[r] = acc[i][j][r] + bc;

            if (MODE == 0) {
                const int sel = col >> 10, within = col & 1023;
                const int h = within >> 6, hd = within & 63;
                const size_t bidx = (size_t)row >> 11, sp = row & 2047;
                if (sel == 0) {
                    // fold softmax scale (1/sqrt(64) * log2e) into Q
#pragma unroll
                    for (int r = 0; r < 4; ++r) v[r] *= 0.18033688011112042f;
                }
                if (sel < 2) {
#pragma unroll
                    for (int r = 0; r < 4; ++r)
                        outb[(size_t)sel * (8192ull * 1024) +
                             ((bidx * 16 + h) * 2048 + sp + r) * 64 + hd] = f2b(v[r]);
                } else {
                    short4 o4;
                    o4.x = f2b(v[0]); o4.y = f2b(v[1]);
                    o4.z = f2b(v[2]); o4.w = f2b(v[3]);
                    *(short4*)&vt[((bidx * 16 + h) * 64 + hd) * 2048 + sp] = o4;
                }
            } else if (MODE == 1) {
#pragma unroll
                for (int r = 0; r < 4; ++r) {
                    const size_t rr = (size_t)(row + r);
                    outf[rr * N + col] = v[r] + resid[rr * N + col];
                }
            } else {
#pragma unroll
                for (int r = 0; r < 4; ++r)
                    outb[(size_t)(row + r) * N + col] = f2b(fast_gelu(v[r]));
            }
        }
    }
}

#undef KTILE
#undef PH_MID
#undef PH_END
#undef MM

// ---------------- causal flash attention v4: S^T formulation, no-max softmax,
// double-buffered K/V (one barrier/iter), XCD-affinity block mapping.
__global__ __launch_bounds__(256) void attn_kernel(
    const short* __restrict__ Q, const short* __restrict__ K,
    const short* __restrict__ Vt, short* __restrict__ O) {
    const int bid = blockIdx.x;
    const int xcd = bid & 7;
    const int sub = (bid >> 3) & 7;    // gq
    const int grp = bid >> 6;          // 0..7
    const int bh  = grp * 8 + xcd;     // bh % 8 == xcd
    const int h = bh & 15, b = bh >> 4;
    const int gq = sub;
    const int tid = threadIdx.x, wave = tid >> 6, lane = tid & 63;
    const int l16 = lane & 15, quad = lane >> 4;

    __shared__ __align__(16) short Ks[2][64 * 72];
    __shared__ __align__(16) short Vts[2][64 * 72];
    __shared__ __align__(16) short Ps[4][16 * 72];

    const size_t bhoff = (size_t)bh * (2048ull * 64);
    const int srow = tid >> 2;
    const int sseg = (tid & 3) * 16;

    const int qts[4] = {gq, 15 - gq, 16 + gq, 31 - gq};

    for (int pass = 0; pass < 4; ++pass) {
        const int qt = qts[pass];
        const int q0 = qt * 64;
        const int q_lane = q0 + wave * 16 + l16;

        const short* qrow = Q + bhoff + (size_t)q_lane * 64;
        s16x8 bq0 = *(const s16x8*)(qrow + quad * 8);
        s16x8 bq1 = *(const s16x8*)(qrow + 32 + quad * 8);

        f32x4 oacc[4] = {};
        float lsum = 0.0f;

        // prologue: load j=0 tile
        s16x8 k0, k1, v0, v1;
        {
            const short* kg = K + bhoff + (size_t)srow * 64 + sseg;
            k0 = *(const s16x8*)kg;
            k1 = *(const s16x8*)(kg + 8);
            const short* vg = Vt + bhoff + (size_t)srow * 2048 + sseg;
            v0 = *(const s16x8*)vg;
            v1 = *(const s16x8*)(vg + 8);
        }

        for (int j = 0; j <= qt; ++j) {
            const int buf = j & 1;
            *(s16x8*)&Ks[buf][srow * 72 + sseg]      = k0;
            *(s16x8*)&Ks[buf][srow * 72 + sseg + 8]  = k1;
            *(s16x8*)&Vts[buf][srow * 72 + sseg]     = v0;
            *(s16x8*)&Vts[buf][srow * 72 + sseg + 8] = v1;
            __syncthreads();

            if (j < qt) {
                const short* kg = K + bhoff + (size_t)((j + 1) * 64 + srow) * 64 + sseg;
                k0 = *(const s16x8*)kg;
                k1 = *(const s16x8*)(kg + 8);
                const short* vg = Vt + bhoff + (size_t)srow * 2048 + (j + 1) * 64 + sseg;
                v0 = *(const s16x8*)vg;
                v1 = *(const s16x8*)(vg + 8);
            }

            f32x4 st[4];
#pragma unroll
            for (int s = 0; s < 4; ++s) {
                s16x8 ak0 = *(const s16x8*)&Ks[buf][(s * 16 + l16) * 72 + quad * 8];
                s16x8 ak1 = *(const s16x8*)&Ks[buf][(s * 16 + l16) * 72 + 32 + quad * 8];
                f32x4 c = {};
                c = mfma16(ak0, bq0, c);
                c = mfma16(ak1, bq1, c);
                st[s] = c;
            }
            if (j == qt) {
#pragma unroll
                for (int s = 0; s < 4; ++s)
#pragma unroll
                    for (int r = 0; r < 4; ++r) {
                        const int t = j * 64 + s * 16 + quad * 4 + r;
                        if (t > q_lane) st[s][r] = -3000.0f;
                    }
            }
            float rs = 0.0f;
#pragma unroll
            for (int s = 0; s < 4; ++s) {
#pragma unroll
                for (int r = 0; r < 4; ++r) {
                    st[s][r] = exp2f(st[s][r]);
                    rs += st[s][r];
                }
                int2 pw;
                pw.x = pk2(st[s][0], st[s][1]);
                pw.y = pk2(st[s][2], st[s][3]);
                *(int2*)&Ps[wave][l16 * 72 + s * 16 + quad * 4] = pw;
            }
            rs += __shfl_xor(rs, 16);
            rs += __shfl_xor(rs, 32);
            lsum += rs;

            asm volatile("s_waitcnt lgkmcnt(0)" ::: "memory");
            s16x8 ap0 = *(const s16x8*)&Ps[wave][l16 * 72 + quad * 8];
            s16x8 ap1 = *(const s16x8*)&Ps[wave][l16 * 72 + 32 + quad * 8];

#pragma unroll
            for (int nt = 0; nt < 4; ++nt) {
                s16x8 bv0 = *(const s16x8*)&Vts[buf][(nt * 16 + l16) * 72 + quad * 8];
                s16x8 bv1 = *(const s16x8*)&Vts[buf][(nt * 16 + l16) * 72 + 32 + quad * 8];
                oacc[nt] = mfma16(ap0, bv0, oacc[nt]);
                oacc[nt] = mfma16(ap1, bv1, oacc[nt]);
            }
        }
        __syncthreads();

        float inv[4];
#pragma unroll
        for (int r = 0; r < 4; ++r)
            inv[r] = 1.0f / __shfl(lsum, quad * 4 + r, 64);
#pragma unroll
        for (int nt = 0; nt < 4; ++nt)
#pragma unroll
            for (int r = 0; r < 4; ++r) {
                const int row = q0 + wave * 16 + quad * 4 + r;
                O[((size_t)b * 2048 + row) * 1024 + h * 64 + nt * 16 + l16] =
                    f2b(oacc[nt][r] * inv[r]);
            }
    }
}

extern "C" void kernel_launch(void* const* d_in, const int* in_sizes, int n_in,
                              void* d_out, int out_size, void* d_ws, size_t ws_size,
                              hipStream_t stream) {
    const float* x     = (const float*)d_in[0];
    const float* Wq    = (const float*)d_in[1];
    const float* Wk    = (const float*)d_in[2];
    const float* Wv    = (const float*)d_in[3];
    const float* bq    = (const float*)d_in[4];
    const float* bk    = (const float*)d_in[5];
    const float* bv    = (const float*)d_in[6];
    const float* Wo    = (const float*)d_in[7];
    const float* bo    = (const float*)d_in[8];
    const float* W1    = (const float*)d_in[9];
    const float* b1    = (const float*)d_in[10];
    const float* W2    = (const float*)d_in[11];
    const float* b2    = (const float*)d_in[12];
    const float* gamma = (const float*)d_in[13];
    const float* beta  = (const float*)d_in[14];
    float* out = (float*)d_out;

    char* ws = (char*)d_ws;
    size_t off = 0;
    auto alloc = [&](size_t bytes) -> char* {
        char* p = ws + off;
        off += (bytes + 255) & ~(size_t)255;
        return p;
    };
    short* h1    = (short*)alloc(8192ull * 1024 * 2);
    short* btqkv = (short*)alloc(3072ull * 1024 * 2);
    short* btwo  = (short*)alloc(1024ull * 1024 * 2);
    short* btw1  = (short*)alloc(4096ull * 1024 * 2);
    short* btw2  = (short*)alloc(1024ull * 4096 * 2);
    float* bqkv  = (float*)alloc(3072ull * 4);
    short* qkv   = (short*)alloc(2ull * 8192 * 1024 * 2);   // Q,K only
    short* vt    = (short*)alloc(8192ull * 1024 * 2);       // V pre-transposed
    short* aout  = (short*)alloc(8192ull * 1024 * 2);
    float* x2    = (float*)alloc(8192ull * 1024 * 4);
    short* h2    = (short*)alloc(8192ull * 1024 * 2);
    short* m1    = (short*)alloc(8192ull * 4096 * 2);

    // weight prep
    transpose_bf16<<<dim3(2, 32, 16), 256, 0, stream>>>(Wq, btqkv, 1024, 64);
    transpose_bf16<<<dim3(2, 32, 16), 256, 0, stream>>>(Wk, btqkv + 1024ull * 1024, 1024, 64);
    transpose_bf16<<<dim3(2, 32, 16), 256, 0, stream>>>(Wv, btqkv + 2ull * 1024 * 1024, 1024, 64);
    transpose_bf16<<<dim3(32, 32, 1), 256, 0, stream>>>(Wo, btwo, 1024, 1024);
    transpose_bf16<<<dim3(128, 32, 1), 256, 0, stream>>>(W1, btw1, 1024, 4096);
    transpose_bf16<<<dim3(32, 128, 1), 256, 0, stream>>>(W2, btw2, 4096, 1024);
    concat_bias<<<12, 256, 0, stream>>>(bq, bk, bv, bqkv);

    // LN1
    ln_bf16<<<8192, 256, 0, stream>>>(x, gamma, beta, h1);
    // QKV projection: 256^2 8-phase kernel (32 m-tiles x 12 n-tiles)
    gemm256<0><<<384, 512, 0, stream>>>(
        h1, btqkv, bqkv, nullptr, nullptr, qkv, vt, 8192, 3072, 1024);
    // attention (XCD-affinity mapping)
    attn_kernel<<<512, 256, 0, stream>>>(
        qkv, qkv + 8192ull * 1024, vt, aout);
    // Wo + residual -> x2 (f32): narrow-N, keep 128^2 kernel
    gemm_bf16<1, 0><<<dim3(8, 64), 512, 0, stream>>>(
        aout, btwo, bo, x, x2, nullptr, nullptr, 8192, 1024, 1024);
    // LN2
    ln_bf16<<<8192, 256, 0, stream>>>(x2, gamma, beta, h2);
    // MLP1 + GELU: 256^2 8-phase kernel (32 x 16 = 512 blocks, 2/CU rounds)
    gemm256<2><<<512, 512, 0, stream>>>(
        h2, btw1, b1, nullptr, nullptr, m1, nullptr, 8192, 4096, 1024);
    // MLP2 + residual -> out (f32), narrow-N long-K: keep 128^2 M-band kernel
    gemm_bf16<1, 1><<<dim3(8, 64), 512, 0, stream>>>(
        m1, btw2, b2, x2, out, nullptr, nullptr, 8192, 1024, 4096);
}

// Round 2
// 530.961 us; speedup vs baseline: 1.0003x; 1.0003x over previous
//
#include <hip/hip_runtime.h>
#include <hip/hip_bf16.h>

typedef __bf16  bf16x8 __attribute__((ext_vector_type(8)));
typedef float   f32x4  __attribute__((ext_vector_type(4)));
typedef short   s16x8  __attribute__((ext_vector_type(8)));

typedef const __attribute__((address_space(1))) void g_void;
typedef __attribute__((address_space(3))) void l_void;

__device__ __forceinline__ short f2b(float x) {
    __hip_bfloat16 h = __float2bfloat16(x);
    return __builtin_bit_cast(short, h);
}

// pack two floats to bf16 pair in one int (lo | hi<<16)
__device__ __forceinline__ int pk2(float lo, float hi) {
    return (int)(unsigned short)f2b(lo) | ((int)f2b(hi) << 16);
}

// fast GELU: tanh form via hardware exp2. gelu(v) = v*t/(t+1),
// t = exp2(K1*(v + 0.044715 v^3)), K1 = 2*log2(e)*0.7978845608.
__device__ __forceinline__ float fast_gelu(float v) {
    const float a = fminf(2.3022082f * (v + 0.044715f * v * v * v), 126.0f);
    const float t = exp2f(a);
    return v * t / (t + 1.0f);
}

__device__ __forceinline__ f32x4 mfma16(s16x8 a, s16x8 b, f32x4 c) {
    return __builtin_amdgcn_mfma_f32_16x16x32_bf16(
        __builtin_bit_cast(bf16x8, a), __builtin_bit_cast(bf16x8, b), c, 0, 0, 0);
}

// ---------------- transpose + fp32 -> bf16 :  src [R,C] f32 -> dst [C,R] bf16
__global__ __launch_bounds__(256) void transpose_bf16(
    const float* __restrict__ src, short* __restrict__ dst, int R, int C) {
    __shared__ float tile[32][33];
    src += (size_t)blockIdx.z * R * C;
    dst += (size_t)blockIdx.z * R * C;
    const int c0 = blockIdx.x * 32, r0 = blockIdx.y * 32;
    const int tx = threadIdx.x & 31, ty = threadIdx.x >> 5;
#pragma unroll
    for (int i = 0; i < 32; i += 8)
        tile[ty + i][tx] = src[(size_t)(r0 + ty + i) * C + c0 + tx];
    __syncthreads();
#pragma unroll
    for (int i = 0; i < 32; i += 8)
        dst[(size_t)(c0 + ty + i) * R + r0 + tx] = f2b(tile[tx][ty + i]);
}

// ---------------- concat q/k/v bias into [3072] f32
__global__ __launch_bounds__(256) void concat_bias(
    const float* __restrict__ bq, const float* __restrict__ bk,
    const float* __restrict__ bv, float* __restrict__ o) {
    int i = blockIdx.x * 256 + threadIdx.x;
    if (i < 1024)      o[i] = bq[i];
    else if (i < 2048) o[i] = bk[i - 1024];
    else if (i < 3072) o[i] = bv[i - 2048];
}

// ---------------- LayerNorm (D=1024) f32 in -> bf16 out. 1 block/row, 256 thr
__global__ __launch_bounds__(256) void ln_bf16(
    const float* __restrict__ x, const float* __restrict__ gamma,
    const float* __restrict__ beta, short* __restrict__ out) {
    __shared__ float red[8];
    const int row = blockIdx.x, tid = threadIdx.x;
    const float4 v = *(const float4*)(x + (size_t)row * 1024 + tid * 4);
    float s = v.x + v.y + v.z + v.w;
    float q = v.x * v.x + v.y * v.y + v.z * v.z + v.w * v.w;
#pragma unroll
    for (int off = 32; off > 0; off >>= 1) {
        s += __shfl_xor(s, off);
        q += __shfl_xor(q, off);
    }
    if ((tid & 63) == 0) { red[(tid >> 6) * 2] = s; red[(tid >> 6) * 2 + 1] = q; }
    __syncthreads();
    s = red[0] + red[2] + red[4] + red[6];
    q = red[1] + red[3] + red[5] + red[7];
    const float mu = s * (1.0f / 1024.0f);
    const float var = q * (1.0f / 1024.0f) - mu * mu;
    const float rs = rsqrtf(var + 1e-5f);
    const float4 g  = *(const float4*)(gamma + tid * 4);
    const float4 bt = *(const float4*)(beta + tid * 4);
    short4 o;
    o.x = f2b((v.x - mu) * rs * g.x + bt.x);
    o.y = f2b((v.y - mu) * rs * g.y + bt.y);
    o.z = f2b((v.z - mu) * rs * g.z + bt.z);
    o.w = f2b((v.w - mu) * rs * g.w + bt.w);
    *(short4*)(out + (size_t)row * 1024 + tid * 4) = o;
}

// ---------------- OLD bf16 MFMA GEMM (128x128, 2-barrier). Kept for the
// narrow-N GEMMs (Wo, MLP2: N=1024 -> only 128 blocks at 256^2 tile).
// MODE 1: out f32 = acc + bias[col] + resid[row*N+col]
template <int MODE, int SWZ>
__global__ __launch_bounds__(512) void gemm_bf16(
    const short* __restrict__ A, const short* __restrict__ Bt,
    const float* __restrict__ bias, const float* __restrict__ resid,
    float* __restrict__ outf, short* __restrict__ outb, short* __restrict__ vt,
    int M, int N, int K) {
    __shared__ __align__(16) short As[2 * 128 * 32];
    __shared__ __align__(16) short Bs[2 * 128 * 32];

    const int tid = threadIdx.x;
    const int wave = tid >> 6, lane = tid & 63;
    const int l16 = lane & 15, quad = lane >> 4;
    const int wm = wave & 3, wn = wave >> 2;   // 4 row-strips x 2 col-strips
    const int gx = gridDim.x;
    const int g = blockIdx.y * gx + blockIdx.x;
    const int xcd = g & 7, s = g >> 3;
    int m0, n0;
    if (SWZ == 0) {                            // N-band (requires gx % 8 == 0)
        const int nband = gx >> 3;
        const int sm = s / nband;
        const int sn = s - sm * nband;
        m0 = sm * 128;
        n0 = (xcd * nband + sn) * 128;
    } else {                                   // M-band (requires gy % 8 == 0)
        const int mband = gridDim.y >> 3;
        const int sm = s / gx;
        m0 = (xcd * mband + sm) * 128;
        n0 = (s - sm * gx) * 128;
    }
    const int lrow = lane >> 2;        // 0..15
    const int lcol = (lane & 3) * 8;   // 16B chunk within a 32-elem panel row

    f32x4 acc[2][4] = {};

    for (int kk = 0; kk < K; kk += 64) {
#pragma unroll
        for (int p = 0; p < 2; ++p) {        // 32-K panel
            const int r = wave * 16 + lrow;  // 8 waves x 16 rows = 128
            const short* ga = A + (size_t)(m0 + r) * K + kk + p * 32 + lcol;
            short* la = &As[p * 4096 + wave * 512];
            __builtin_amdgcn_global_load_lds((g_void*)ga, (l_void*)la, 16, 0, 0);
            const short* gb = Bt + (size_t)(n0 + r) * K + kk + p * 32 + lcol;
            short* lb = &Bs[p * 4096 + wave * 512];
            __builtin_amdgcn_global_load_lds((g_void*)gb, (l_void*)lb, 16, 0, 0);
        }
        __syncthreads();
#pragma unroll
        for (int p = 0; p < 2; ++p) {
            s16x8 a[2], b[4];
#pragma unroll
            for (int t = 0; t < 2; ++t)
                a[t] = *(const s16x8*)&As[p * 4096 + (wm * 32 + t * 16 + l16) * 32 + quad * 8];
#pragma unroll
            for (int t = 0; t < 4; ++t)
                b[t] = *(const s16x8*)&Bs[p * 4096 + (wn * 64 + t * 16 + l16) * 32 + quad * 8];
#pragma unroll
            for (int mt = 0; mt < 2; ++mt)
#pragma unroll
                for (int nt = 0; nt < 4; ++nt)
                    acc[mt][nt] = mfma16(a[mt], b[nt], acc[mt][nt]);
        }
        __syncthreads();
    }

#pragma unroll
    for (int mt = 0; mt < 2; ++mt) {
#pragma unroll
        for (int nt = 0; nt < 4; ++nt) {
            const int row = m0 + wm * 32 + mt * 16 + quad * 4;   // + r
            const int col = n0 + wn * 64 + nt * 16 + l16;
            const float bc = bias[col];
            float v[4];
#pragma unroll
            for (int r = 0; r < 4; ++r) v[r] = acc[mt][nt][r] + bc;

            if (MODE == 1) {
#pragma unroll
                for (int r = 0; r < 4; ++r) {
                    const size_t rr = (size_t)(row + r);
                    outf[rr * N + col] = v[r] + resid[rr * N + col];
                }
            } else {
#pragma unroll
                for (int r = 0; r < 4; ++r)
                    outb[(size_t)(row + r) * N + col] = f2b(fast_gelu(v[r]));
            }
        }
    }
}

// ======================= 256x256 8-phase GEMM (T2+T3+T4+T5) ==================
// BM=BN=256, BK=64, 512 threads = 8 waves (2M x 4N), per-wave 128x64 output.
// LDS: A,B each 2 bufs x 2 halves x (128x64) bf16 = 64 KiB -> 128 KiB total.
// st_16x32 swizzle; global_load_lds writes LINEAR chunks, global SOURCE is
// inverse-swizzled per-thread, reads use swizzled addr (rule #21).
//
// m201-faithful schedule (reconstructed from the documented vmcnt numbers):
// one half-tile staged per phase, B halves before A halves, each half staged
// at the earliest phase after its last LDS read; stages issued POST-MFMA
// (after the mid-barrier+lgkmcnt(0) all waves passed) for extra race margin.
// Slots per iteration (buf0 = K-tile T=2it read P1-P4, buf1 = T+1 read P5-P8):
//   P1: A<buf1>h1 (k=T+1, completes buf1)   P5: A<buf0>h1 (k=T+2, completes)
//   P2: B<buf0>h0 (k=T+2 refill)            P6: B<buf1>h0 (k=T+3 refill)
//   P3: B<buf0>h1                           P7: B<buf1>h1
//   P4: A<buf0>h0 + vmcnt(6)                P8: A<buf1>h0 + vmcnt(6)
// vmcnt(6) = 3 half-tiles in flight; confirm-set at P4 = the 4 halves of the
// next-consumed K-tile (staged 4-7 phases earlier -> HBM latency hidden).
// Prologue: stage buf0 {Bh0,Bh1,Ah0,Ah1}, vmcnt(4); stage buf1 {Bh0,Bh1,Ah0},
// vmcnt(6); barrier.  (A<buf1>h1 is staged in-loop at P1.)

#define MM(MH, NH, AF, BB)                                                   \
    _Pragma("unroll") for (int p = 0; p < 2; ++p)                            \
        _Pragma("unroll") for (int ii = 0; ii < 4; ++ii)                     \
            _Pragma("unroll") for (int jj = 0; jj < 2; ++jj)                 \
                acc[(MH) * 4 + ii][(NH) * 2 + jj] =                          \
                    mfma16(AF[ii][p], BB[jj][p],                             \
                           acc[(MH) * 4 + ii][(NH) * 2 + jj]);

// mid-phase: barrier, full lgkm drain (template-exact), pin, raise prio
#define PH_A                                                                 \
    __builtin_amdgcn_s_barrier();                                            \
    asm volatile("s_waitcnt lgkmcnt(0)" ::: "memory");                       \
    __builtin_amdgcn_sched_barrier(0);                                       \
    __builtin_amdgcn_s_setprio(1);

// post-MFMA: drop prio, pin so the stage can't float above the MFMAs
#define PH_B                                                                 \
    __builtin_amdgcn_s_setprio(0);                                           \
    __builtin_amdgcn_sched_barrier(0);

// phase end barrier
#define PH_C                                                                 \
    __builtin_amdgcn_sched_barrier(0);                                       \
    __builtin_amdgcn_s_barrier();                                            \
    __builtin_amdgcn_sched_barrier(0);

// 4 phases of one K-tile in buffer BUF; S1..S4 = per-phase stage statements
// (issued post-MFMA, pre-end-barrier). vmcnt(6) after S4.
#define KTILE(BUF, S1, S2, S3, S4)                                           \
    {                                                                        \
        s16x8 af[4][2], bl[2][2], bh[2][2];                                  \
        /* P1: quadrant (0,0), 12 ds_reads */                                \
        _Pragma("unroll") for (int ii = 0; ii < 4; ++ii)                     \
            _Pragma("unroll") for (int p = 0; p < 2; ++p)                    \
                af[ii][p] = LDA(BUF, ii, p);                                 \
        _Pragma("unroll") for (int jj = 0; jj < 2; ++jj)                     \
            _Pragma("unroll") for (int p = 0; p < 2; ++p)                    \
                bl[jj][p] = LDB(BUF, jj, p);                                 \
        asm volatile("s_waitcnt lgkmcnt(8)" ::: "memory");                   \
        PH_A;                                                                \
        MM(0, 0, af, bl);                                                    \
        PH_B;                                                                \
        S1;                                                                  \
        PH_C;                                                                \
        /* P2: quadrant (0,1), 4 ds_reads */                                 \
        _Pragma("unroll") for (int jj = 0; jj < 2; ++jj)                     \
            _Pragma("unroll") for (int p = 0; p < 2; ++p)                    \
                bh[jj][p] = LDB(BUF, 2 + jj, p);                             \
        PH_A;                                                                \
        MM(0, 1, af, bh);                                                    \
        PH_B;                                                                \
        S2;                                                                  \
        PH_C;                                                                \
        /* P3: quadrant (1,1), 8 ds_reads */                                 \
        _Pragma("unroll") for (int ii = 0; ii < 4; ++ii)                     \
            _Pragma("unroll") for (int p = 0; p < 2; ++p)                    \
                af[ii][p] = LDA(BUF, 4 + ii, p);                             \
        PH_A;                                                                \
        MM(1, 1, af, bh);                                                    \
        PH_B;                                                                \
        S3;                                                                  \
        PH_C;                                                                \
        /* P4: quadrant (1,0), 0 ds_reads, counted vmcnt */                  \
        PH_A;                                                                \
        MM(1, 0, af, bl);                                                    \
        PH_B;                                                                \
        S4;                                                                  \
        asm volatile("s_waitcnt vmcnt(6)" ::: "memory");                     \
        PH_C;                                                                \
    }

// MODE 0: QKV scatter (Q pre-scaled, K -> [2][B,H,S,HD], V -> vt [B,H,HD,S])
// MODE 1: out f32 = acc + bias[col] + resid   MODE 2: out bf16 = gelu(acc+b)
template <int MODE>
__global__ __launch_bounds__(512, 2) void gemm256(
    const short* __restrict__ A, const short* __restrict__ Bt,
    const float* __restrict__ bias, const float* __restrict__ resid,
    float* __restrict__ outf, short* __restrict__ outb, short* __restrict__ vt,
    int M, int N, int K) {
    __shared__ __align__(16) short As[32768];   // 2 bufs x 2 halves x 8192
    __shared__ __align__(16) short Bs[32768];

    const int tid = threadIdx.x;
    const int wave = tid >> 6, lane = tid & 63;
    const int l16 = lane & 15, quad = lane >> 4;
    const int wm = wave >> 2, wn = wave & 3;    // 2 x 4 wave grid

    // XCD-chunked bijective swizzle (gridDim.x % 8 == 0), m-fastest order:
    // each XCD sweeps full m-columns of one n-band -> B-slice L2-resident.
    const int nwg = gridDim.x;
    const int g = blockIdx.x;
    const int wgid = (g & 7) * (nwg >> 3) + (g >> 3);
    const int mtiles = M >> 8;
    const int m0 = (wgid % mtiles) << 8;
    const int n0 = (wgid / mtiles) << 8;

    // ---- read-side swizzled offsets (in shorts)
    // lin = (sr*2+p)*512 + l16*32 + quad*8 ; swizzle flips short-bit4 (32B)
    // by short-bit8 (= l16>>3).
    const int rc = l16 * 32 + ((quad * 8) ^ ((l16 >> 3) << 4));
    const int a_rd = wm * 8192 + rc;                    // + (i*2+p)*512
    const int b_rd = (wn >> 1) * 8192 + (wn & 1) * 4096 + rc;

    auto LDA = [&](int buf, int i, int p) {
        return *(const s16x8*)&As[buf * 16384 + a_rd + (i * 2 + p) * 512];
    };
    auto LDB = [&](int buf, int j, int p) {
        return *(const s16x8*)&Bs[buf * 16384 + b_rd + (j * 2 + p) * 512];
    };

    // ---- stage-side inverse mapping: linear LDS chunk s=c*16 holds element
    // (r, col): lin = s ^ (((s>>9)&1)<<5); st=lin>>10; r=(st>>1)*16+((lin>>6)&15);
    // col = (st&1)*32 + ((lin&63)>>1).
    int r0, c0, r1, c1;
    {
        int s = tid * 16;
        int lin = s ^ (((s >> 9) & 1) << 5);
        r0 = ((lin >> 11) << 4) + ((lin >> 6) & 15);
        c0 = (((lin >> 10) & 1) << 5) + ((lin & 63) >> 1);
        s = (tid + 512) * 16;
        lin = s ^ (((s >> 9) & 1) << 5);
        r1 = ((lin >> 11) << 4) + ((lin >> 6) & 15);
        c1 = (((lin >> 10) & 1) << 5) + ((lin & 63) >> 1);
    }

    const short* gA = A + (size_t)m0 * K;
    const short* gB = Bt + (size_t)n0 * K;

    auto STAGE = [&](const short* gbase, int half, int kk, short* lds) {
        const short* s0 = gbase + (size_t)(half * 128 + r0) * K + kk + c0;
        const short* s1 = gbase + (size_t)(half * 128 + r1) * K + kk + c1;
        short* d0 = lds + half * 8192 + wave * 512;
        short* d1 = lds + half * 8192 + 4096 + wave * 512;
        __builtin_amdgcn_global_load_lds((g_void*)s0, (l_void*)d0, 16, 0, 0);
        __builtin_amdgcn_global_load_lds((g_void*)s1, (l_void*)d1, 16, 0, 0);
    };

    f32x4 acc[8][4] = {};

    // prologue (template-exact): buf0 {B,A}, vmcnt(4); buf1 {B,Ah0}, vmcnt(6)
    STAGE(gB, 0, 0, Bs);
    STAGE(gB, 1, 0, Bs);
    STAGE(gA, 0, 0, As);
    STAGE(gA, 1, 0, As);
    asm volatile("s_waitcnt vmcnt(4)" ::: "memory");
    STAGE(gB, 0, 64, Bs + 16384);
    STAGE(gB, 1, 64, Bs + 16384);
    STAGE(gA, 0, 64, As + 16384);
    asm volatile("s_waitcnt vmcnt(6)" ::: "memory");   // buf0 complete
    __builtin_amdgcn_s_barrier();
    __builtin_amdgcn_sched_barrier(0);

    const int NI = K >> 7;                              // 2 K-tiles / iter
    for (int it = 0; it < NI; ++it) {
        const int kT1 = (2 * it + 1) * 64;              // buf1 A h1 (current)
        int kT2 = (2 * it + 2) * 64;                    // buf0 refill
        if (kT2 > K - 64) kT2 = K - 64;                 // clamp (unused dup)
        int kT3 = (2 * it + 3) * 64;                    // buf1 refill
        if (kT3 > K - 64) kT3 = K - 64;

        KTILE(0,
              STAGE(gA, 1, kT1, As + 16384),            // P1: A buf1 h1
              STAGE(gB, 0, kT2, Bs),                    // P2: B buf0 h0
              STAGE(gB, 1, kT2, Bs),                    // P3: B buf0 h1
              STAGE(gA, 0, kT2, As));                   // P4: A buf0 h0
        KTILE(1,
              STAGE(gA, 1, kT2, As),                    // P5: A buf0 h1
              STAGE(gB, 0, kT3, Bs + 16384),            // P6: B buf1 h0
              STAGE(gB, 1, kT3, Bs + 16384),            // P7: B buf1 h1
              STAGE(gA, 0, kT3, As + 16384));           // P8: A buf1 h0
    }
    asm volatile("s_waitcnt vmcnt(0)" ::: "memory");    // drain trailing stages

    // ---- epilogue
#pragma unroll
    for (int i = 0; i < 8; ++i) {
#pragma unroll
        for (int j = 0; j < 4; ++j) {
            const int row = m0 + wm * 128 + i * 16 + quad * 4;   // + r
            const int col = n0 + wn * 64 + j * 16 + l16;
            const float bc = bias[col];
            float v[4];
#pragma unroll
            for (int r = 0; r < 4; ++r) v[r] = acc[i][j][r] + bc;

            if (MODE == 0) {
                const int sel = col >> 10, within = col & 1023;
                const int h = within >> 6, hd = within & 63;
                const size_t bidx = (size_t)row >> 11, sp = row & 2047;
                if (sel == 0) {
                    // fold softmax scale (1/sqrt(64) * log2e) into Q
#pragma unroll
                    for (int r = 0; r < 4; ++r) v[r] *= 0.18033688011112042f;
                }
                if (sel < 2) {
#pragma unroll
                    for (int r = 0; r < 4; ++r)
                        outb[(size_t)sel * (8192ull * 1024) +
                             ((bidx * 16 + h) * 2048 + sp + r) * 64 + hd] = f2b(v[r]);
                } else {
                    short4 o4;
                    o4.x = f2b(v[0]); o4.y = f2b(v[1]);
                    o4.z = f2b(v[2]); o4.w = f2b(v[3]);
                    *(short4*)&vt[((bidx * 16 + h) * 64 + hd) * 2048 + sp] = o4;
                }
            } else if (MODE == 1) {
#pragma unroll
                for (int r = 0; r < 4; ++r) {
                    const size_t rr = (size_t)(row + r);
                    outf[rr * N + col] = v[r] + resid[rr * N + col];
                }
            } else {
#pragma unroll
                for (int r = 0; r < 4; ++r)
                    outb[(size_t)(row + r) * N + col] = f2b(fast_gelu(v[r]));
            }
        }
    }
}

#undef KTILE
#undef PH_A
#undef PH_B
#undef PH_C
#undef MM

// ---------------- causal flash attention v4: S^T formulation, no-max softmax,
// double-buffered K/V (one barrier/iter), XCD-affinity block mapping.
__global__ __launch_bounds__(256) void attn_kernel(
    const short* __restrict__ Q, const short* __restrict__ K,
    const short* __restrict__ Vt, short* __restrict__ O) {
    const int bid = blockIdx.x;
    const int xcd = bid & 7;
    const int sub = (bid >> 3) & 7;    // gq
    const int grp = bid >> 6;          // 0..7
    const int bh  = grp * 8 + xcd;     // bh % 8 == xcd
    const int h = bh & 15, b = bh >> 4;
    const int gq = sub;
    const int tid = threadIdx.x, wave = tid >> 6, lane = tid & 63;
    const int l16 = lane & 15, quad = lane >> 4;

    __shared__ __align__(16) short Ks[2][64 * 72];
    __shared__ __align__(16) short Vts[2][64 * 72];
    __shared__ __align__(16) short Ps[4][16 * 72];

    const size_t bhoff = (size_t)bh * (2048ull * 64);
    const int srow = tid >> 2;
    const int sseg = (tid & 3) * 16;

    const int qts[4] = {gq, 15 - gq, 16 + gq, 31 - gq};

    for (int pass = 0; pass < 4; ++pass) {
        const int qt = qts[pass];
        const int q0 = qt * 64;
        const int q_lane = q0 + wave * 16 + l16;

        const short* qrow = Q + bhoff + (size_t)q_lane * 64;
        s16x8 bq0 = *(const s16x8*)(qrow + quad * 8);
        s16x8 bq1 = *(const s16x8*)(qrow + 32 + quad * 8);

        f32x4 oacc[4] = {};
        float lsum = 0.0f;

        // prologue: load j=0 tile
        s16x8 k0, k1, v0, v1;
        {
            const short* kg = K + bhoff + (size_t)srow * 64 + sseg;
            k0 = *(const s16x8*)kg;
            k1 = *(const s16x8*)(kg + 8);
            const short* vg = Vt + bhoff + (size_t)srow * 2048 + sseg;
            v0 = *(const s16x8*)vg;
            v1 = *(const s16x8*)(vg + 8);
        }

        for (int j = 0; j <= qt; ++j) {
            const int buf = j & 1;
            *(s16x8*)&Ks[buf][srow * 72 + sseg]      = k0;
            *(s16x8*)&Ks[buf][srow * 72 + sseg + 8]  = k1;
            *(s16x8*)&Vts[buf][srow * 72 + sseg]     = v0;
            *(s16x8*)&Vts[buf][srow * 72 + sseg + 8] = v1;
            __syncthreads();

            if (j < qt) {
                const short* kg = K + bhoff + (size_t)((j + 1) * 64 + srow) * 64 + sseg;
                k0 = *(const s16x8*)kg;
                k1 = *(const s16x8*)(kg + 8);
                const short* vg = Vt + bhoff + (size_t)srow * 2048 + (j + 1) * 64 + sseg;
                v0 = *(const s16x8*)vg;
                v1 = *(const s16x8*)(vg + 8);
            }

            f32x4 st[4];
#pragma unroll
            for (int s = 0; s < 4; ++s) {
                s16x8 ak0 = *(const s16x8*)&Ks[buf][(s * 16 + l16) * 72 + quad * 8];
                s16x8 ak1 = *(const s16x8*)&Ks[buf][(s * 16 + l16) * 72 + 32 + quad * 8];
                f32x4 c = {};
                c = mfma16(ak0, bq0, c);
                c = mfma16(ak1, bq1, c);
                st[s] = c;
            }
            if (j == qt) {
#pragma unroll
                for (int s = 0; s < 4; ++s)
#pragma unroll
                    for (int r = 0; r < 4; ++r) {
                        const int t = j * 64 + s * 16 + quad * 4 + r;
                        if (t > q_lane) st[s][r] = -3000.0f;
                    }
            }
            float rs = 0.0f;
#pragma unroll
            for (int s = 0; s < 4; ++s) {
#pragma unroll
                for (int r = 0; r < 4; ++r) {
                    st[s][r] = exp2f(st[s][r]);
                    rs += st[s][r];
                }
                int2 pw;
                pw.x = pk2(st[s][0], st[s][1]);
                pw.y = pk2(st[s][2], st[s][3]);
                *(int2*)&Ps[wave][l16 * 72 + s * 16 + quad * 4] = pw;
            }
            rs += __shfl_xor(rs, 16);
            rs += __shfl_xor(rs, 32);
            lsum += rs;

            asm volatile("s_waitcnt lgkmcnt(0)" ::: "memory");
            s16x8 ap0 = *(const s16x8*)&Ps[wave][l16 * 72 + quad * 8];
            s16x8 ap1 = *(const s16x8*)&Ps[wave][l16 * 72 + 32 + quad * 8];

#pragma unroll
            for (int nt = 0; nt < 4; ++nt) {
                s16x8 bv0 = *(const s16x8*)&Vts[buf][(nt * 16 + l16) * 72 + quad * 8];
                s16x8 bv1 = *(const s16x8*)&Vts[buf][(nt * 16 + l16) * 72 + 32 + quad * 8];
                oacc[nt] = mfma16(ap0, bv0, oacc[nt]);
                oacc[nt] = mfma16(ap1, bv1, oacc[nt]);
            }
        }
        __syncthreads();

        float inv[4];
#pragma unroll
        for (int r = 0; r < 4; ++r)
            inv[r] = 1.0f / __shfl(lsum, quad * 4 + r, 64);
#pragma unroll
        for (int nt = 0; nt < 4; ++nt)
#pragma unroll
            for (int r = 0; r < 4; ++r) {
                const int row = q0 + wave * 16 + quad * 4 + r;
                O[((size_t)b * 2048 + row) * 1024 + h * 64 + nt * 16 + l16] =
                    f2b(oacc[nt][r] * inv[r]);
            }
    }
}

extern "C" void kernel_launch(void* const* d_in, const int* in_sizes, int n_in,
                              void* d_out, int out_size, void* d_ws, size_t ws_size,
                              hipStream_t stream) {
    const float* x     = (const float*)d_in[0];
    const float* Wq    = (const float*)d_in[1];
    const float* Wk    = (const float*)d_in[2];
    const float* Wv    = (const float*)d_in[3];
    const float* bq    = (const float*)d_in[4];
    const float* bk    = (const float*)d_in[5];
    const float* bv    = (const float*)d_in[6];
    const float* Wo    = (const float*)d_in[7];
    const float* bo    = (const float*)d_in[8];
    const float* W1    = (const float*)d_in[9];
    const float* b1    = (const float*)d_in[10];
    const float* W2    = (const float*)d_in[11];
    const float* b2    = (const float*)d_in[12];
    const float* gamma = (const float*)d_in[13];
    const float* beta  = (const float*)d_in[14];
    float* out = (float*)d_out;

    char* ws = (char*)d_ws;
    size_t off = 0;
    auto alloc = [&](size_t bytes) -> char* {
        char* p = ws + off;
        off += (bytes + 255) & ~(size_t)255;
        return p;
    };
    short* h1    = (short*)alloc(8192ull * 1024 * 2);
    short* btqkv = (short*)alloc(3072ull * 1024 * 2);
    short* btwo  = (short*)alloc(1024ull * 1024 * 2);
    short* btw1  = (short*)alloc(4096ull * 1024 * 2);
    short* btw2  = (short*)alloc(1024ull * 4096 * 2);
    float* bqkv  = (float*)alloc(3072ull * 4);
    short* qkv   = (short*)alloc(2ull * 8192 * 1024 * 2);   // Q,K only
    short* vt    = (short*)alloc(8192ull * 1024 * 2);       // V pre-transposed
    short* aout  = (short*)alloc(8192ull * 1024 * 2);
    float* x2    = (float*)alloc(8192ull * 1024 * 4);
    short* h2    = (short*)alloc(8192ull * 1024 * 2);
    short* m1    = (short*)alloc(8192ull * 4096 * 2);

    // weight prep
    transpose_bf16<<<dim3(2, 32, 16), 256, 0, stream>>>(Wq, btqkv, 1024, 64);
    transpose_bf16<<<dim3(2, 32, 16), 256, 0, stream>>>(Wk, btqkv + 1024ull * 1024, 1024, 64);
    transpose_bf16<<<dim3(2, 32, 16), 256, 0, stream>>>(Wv, btqkv + 2ull * 1024 * 1024, 1024, 64);
    transpose_bf16<<<dim3(32, 32, 1), 256, 0, stream>>>(Wo, btwo, 1024, 1024);
    transpose_bf16<<<dim3(128, 32, 1), 256, 0, stream>>>(W1, btw1, 1024, 4096);
    transpose_bf16<<<dim3(32, 128, 1), 256, 0, stream>>>(W2, btw2, 4096, 1024);
    concat_bias<<<12, 256, 0, stream>>>(bq, bk, bv, bqkv);

    // LN1
    ln_bf16<<<8192, 256, 0, stream>>>(x, gamma, beta, h1);
    // QKV projection: 256^2 8-phase kernel (32 m-tiles x 12 n-tiles)
    gemm256<0><<<384, 512, 0, stream>>>(
        h1, btqkv, bqkv, nullptr, nullptr, qkv, vt, 8192, 3072, 1024);
    // attention (XCD-affinity mapping)
    attn_kernel<<<512, 256, 0, stream>>>(
        qkv, qkv + 8192ull * 1024, vt, aout);
    // Wo + residual -> x2 (f32): narrow-N, keep 128^2 kernel
    gemm_bf16<1, 0><<<dim3(8, 64), 512, 0, stream>>>(
        aout, btwo, bo, x, x2, nullptr, nullptr, 8192, 1024, 1024);
    // LN2
    ln_bf16<<<8192, 256, 0, stream>>>(x2, gamma, beta, h2);
    // MLP1 + GELU: 256^2 8-phase kernel (32 x 16 = 512 blocks, 2/CU rounds)
    gemm256<2><<<512, 512, 0, stream>>>(
        h2, btw1, b1, nullptr, nullptr, m1, nullptr, 8192, 4096, 1024);
    // MLP2 + residual -> out (f32), narrow-N long-K: keep 128^2 M-band kernel
    gemm_bf16<1, 1><<<dim3(8, 64), 512, 0, stream>>>(
        m1, btw2, b2, x2, out, nullptr, nullptr, 8192, 1024, 4096);
}

// Round 3
// 527.115 us; speedup vs baseline: 1.0076x; 1.0073x over previous
//
#include <hip/hip_runtime.h>
#include <hip/hip_bf16.h>

typedef __bf16  bf16x8 __attribute__((ext_vector_type(8)));
typedef float   f32x4  __attribute__((ext_vector_type(4)));
typedef short   s16x8  __attribute__((ext_vector_type(8)));

typedef const __attribute__((address_space(1))) void g_void;
typedef __attribute__((address_space(3))) void l_void;

__device__ __forceinline__ short f2b(float x) {
    __hip_bfloat16 h = __float2bfloat16(x);
    return __builtin_bit_cast(short, h);
}

// pack two floats to bf16 pair in one int (lo | hi<<16)
__device__ __forceinline__ int pk2(float lo, float hi) {
    return (int)(unsigned short)f2b(lo) | ((int)f2b(hi) << 16);
}

// fast GELU: tanh form via hardware exp2. gelu(v) = v*t/(t+1),
// t = exp2(K1*(v + 0.044715 v^3)), K1 = 2*log2(e)*0.7978845608.
__device__ __forceinline__ float fast_gelu(float v) {
    const float a = fminf(2.3022082f * (v + 0.044715f * v * v * v), 126.0f);
    const float t = exp2f(a);
    return v * t / (t + 1.0f);
}

__device__ __forceinline__ f32x4 mfma16(s16x8 a, s16x8 b, f32x4 c) {
    return __builtin_amdgcn_mfma_f32_16x16x32_bf16(
        __builtin_bit_cast(bf16x8, a), __builtin_bit_cast(bf16x8, b), c, 0, 0, 0);
}

// ---------------- transpose + fp32 -> bf16 :  src [R,C] f32 -> dst [C,R] bf16
__global__ __launch_bounds__(256) void transpose_bf16(
    const float* __restrict__ src, short* __restrict__ dst, int R, int C) {
    __shared__ float tile[32][33];
    src += (size_t)blockIdx.z * R * C;
    dst += (size_t)blockIdx.z * R * C;
    const int c0 = blockIdx.x * 32, r0 = blockIdx.y * 32;
    const int tx = threadIdx.x & 31, ty = threadIdx.x >> 5;
#pragma unroll
    for (int i = 0; i < 32; i += 8)
        tile[ty + i][tx] = src[(size_t)(r0 + ty + i) * C + c0 + tx];
    __syncthreads();
#pragma unroll
    for (int i = 0; i < 32; i += 8)
        dst[(size_t)(c0 + ty + i) * R + r0 + tx] = f2b(tile[tx][ty + i]);
}

// ---------------- concat q/k/v bias into [3072] f32
__global__ __launch_bounds__(256) void concat_bias(
    const float* __restrict__ bq, const float* __restrict__ bk,
    const float* __restrict__ bv, float* __restrict__ o) {
    int i = blockIdx.x * 256 + threadIdx.x;
    if (i < 1024)      o[i] = bq[i];
    else if (i < 2048) o[i] = bk[i - 1024];
    else if (i < 3072) o[i] = bv[i - 2048];
}

// ---------------- LayerNorm (D=1024) f32 in -> bf16 out. 1 block/row, 256 thr
__global__ __launch_bounds__(256) void ln_bf16(
    const float* __restrict__ x, const float* __restrict__ gamma,
    const float* __restrict__ beta, short* __restrict__ out) {
    __shared__ float red[8];
    const int row = blockIdx.x, tid = threadIdx.x;
    const float4 v = *(const float4*)(x + (size_t)row * 1024 + tid * 4);
    float s = v.x + v.y + v.z + v.w;
    float q = v.x * v.x + v.y * v.y + v.z * v.z + v.w * v.w;
#pragma unroll
    for (int off = 32; off > 0; off >>= 1) {
        s += __shfl_xor(s, off);
        q += __shfl_xor(q, off);
    }
    if ((tid & 63) == 0) { red[(tid >> 6) * 2] = s; red[(tid >> 6) * 2 + 1] = q; }
    __syncthreads();
    s = red[0] + red[2] + red[4] + red[6];
    q = red[1] + red[3] + red[5] + red[7];
    const float mu = s * (1.0f / 1024.0f);
    const float var = q * (1.0f / 1024.0f) - mu * mu;
    const float rs = rsqrtf(var + 1e-5f);
    const float4 g  = *(const float4*)(gamma + tid * 4);
    const float4 bt = *(const float4*)(beta + tid * 4);
    short4 o;
    o.x = f2b((v.x - mu) * rs * g.x + bt.x);
    o.y = f2b((v.y - mu) * rs * g.y + bt.y);
    o.z = f2b((v.z - mu) * rs * g.z + bt.z);
    o.w = f2b((v.w - mu) * rs * g.w + bt.w);
    *(short4*)(out + (size_t)row * 1024 + tid * 4) = o;
}

// ---------------- bf16 MFMA GEMM (128x128, 2-barrier) for narrow-N GEMMs.
// MODE 0: QKV scatter  MODE 1: f32 = acc+bias+resid  MODE 2: bf16 gelu(acc+b)
template <int MODE, int SWZ>
__global__ __launch_bounds__(512) void gemm_bf16(
    const short* __restrict__ A, const short* __restrict__ Bt,
    const float* __restrict__ bias, const float* __restrict__ resid,
    float* __restrict__ outf, short* __restrict__ outb, short* __restrict__ vt,
    int M, int N, int K) {
    __shared__ __align__(16) short As[2 * 128 * 32];
    __shared__ __align__(16) short Bs[2 * 128 * 32];

    const int tid = threadIdx.x;
    const int wave = tid >> 6, lane = tid & 63;
    const int l16 = lane & 15, quad = lane >> 4;
    const int wm = wave & 3, wn = wave >> 2;   // 4 row-strips x 2 col-strips
    const int gx = gridDim.x;
    const int g = blockIdx.y * gx + blockIdx.x;
    const int xcd = g & 7, s = g >> 3;
    int m0, n0;
    if (SWZ == 0) {                            // N-band (requires gx % 8 == 0)
        const int nband = gx >> 3;
        const int sm = s / nband;
        const int sn = s - sm * nband;
        m0 = sm * 128;
        n0 = (xcd * nband + sn) * 128;
    } else {                                   // M-band (requires gy % 8 == 0)
        const int mband = gridDim.y >> 3;
        const int sm = s / gx;
        m0 = (xcd * mband + sm) * 128;
        n0 = (s - sm * gx) * 128;
    }
    const int lrow = lane >> 2;        // 0..15
    const int lcol = (lane & 3) * 8;   // 16B chunk within a 32-elem panel row

    f32x4 acc[2][4] = {};

    for (int kk = 0; kk < K; kk += 64) {
#pragma unroll
        for (int p = 0; p < 2; ++p) {        // 32-K panel
            const int r = wave * 16 + lrow;  // 8 waves x 16 rows = 128
            const short* ga = A + (size_t)(m0 + r) * K + kk + p * 32 + lcol;
            short* la = &As[p * 4096 + wave * 512];
            __builtin_amdgcn_global_load_lds((g_void*)ga, (l_void*)la, 16, 0, 0);
            const short* gb = Bt + (size_t)(n0 + r) * K + kk + p * 32 + lcol;
            short* lb = &Bs[p * 4096 + wave * 512];
            __builtin_amdgcn_global_load_lds((g_void*)gb, (l_void*)lb, 16, 0, 0);
        }
        __syncthreads();
#pragma unroll
        for (int p = 0; p < 2; ++p) {
            s16x8 a[2], b[4];
#pragma unroll
            for (int t = 0; t < 2; ++t)
                a[t] = *(const s16x8*)&As[p * 4096 + (wm * 32 + t * 16 + l16) * 32 + quad * 8];
#pragma unroll
            for (int t = 0; t < 4; ++t)
                b[t] = *(const s16x8*)&Bs[p * 4096 + (wn * 64 + t * 16 + l16) * 32 + quad * 8];
#pragma unroll
            for (int mt = 0; mt < 2; ++mt)
#pragma unroll
                for (int nt = 0; nt < 4; ++nt)
                    acc[mt][nt] = mfma16(a[mt], b[nt], acc[mt][nt]);
        }
        __syncthreads();
    }

#pragma unroll
    for (int mt = 0; mt < 2; ++mt) {
#pragma unroll
        for (int nt = 0; nt < 4; ++nt) {
            const int row = m0 + wm * 32 + mt * 16 + quad * 4;   // + r
            const int col = n0 + wn * 64 + nt * 16 + l16;
            const float bc = bias[col];
            float v[4];
#pragma unroll
            for (int r = 0; r < 4; ++r) v[r] = acc[mt][nt][r] + bc;

            if (MODE == 0) {
                const int sel = col >> 10, within = col & 1023;
                const int h = within >> 6, hd = within & 63;
                const size_t bidx = (size_t)row >> 11, sp = row & 2047;
                if (sel == 0) {
#pragma unroll
                    for (int r = 0; r < 4; ++r) v[r] *= 0.18033688011112042f;
                }
                if (sel < 2) {
#pragma unroll
                    for (int r = 0; r < 4; ++r)
                        outb[(size_t)sel * (8192ull * 1024) +
                             ((bidx * 16 + h) * 2048 + sp + r) * 64 + hd] = f2b(v[r]);
                } else {
                    short4 o4;
                    o4.x = f2b(v[0]); o4.y = f2b(v[1]);
                    o4.z = f2b(v[2]); o4.w = f2b(v[3]);
                    *(short4*)&vt[((bidx * 16 + h) * 64 + hd) * 2048 + sp] = o4;
                }
            } else if (MODE == 1) {
#pragma unroll
                for (int r = 0; r < 4; ++r) {
                    const size_t rr = (size_t)(row + r);
                    outf[rr * N + col] = v[r] + resid[rr * N + col];
                }
            } else {
#pragma unroll
                for (int r = 0; r < 4; ++r)
                    outb[(size_t)(row + r) * N + col] = f2b(fast_gelu(v[r]));
            }
        }
    }
}

// ======================= 256x256 8-phase GEMM v3 =============================
// R1 placement (reads + stage at phase TOP, pre-barrier: LDS reads and stage
// issue overlap the previous phase's MFMA drain) + deep-confirm slots:
// per K-tile phases stage {A<next-buf>h0, A<next-buf>h1, B<cur-buf>h0,
// B<cur-buf>h1}; vmcnt(4) AFTER the MFMA cluster of P4/P8 only.
// Steady state: 4 loads (one B tile) always in flight; every confirmed load
// was issued 2.5-5 phases earlier. Hazards: every stage issues >=1 barrier
// after the overwritten half's last lgkm-confirmed read:
//   P1,P2: A<buf1> (old contents last read prev P7)      -> k = T+1
//   P3,P4: B<buf0> (last read P2)                        -> k = T+2
//   P5,P6: A<buf0> (last read P3)                        -> k = T+2
//   P7,P8: B<buf1> (last read P6)                        -> k = T+3
// vmcnt(4)@P4-end confirms {prev B<buf1>, A<buf1>} -> buf1 ready for P5.
// vmcnt(4)@P8-end confirms {B<buf0>, A<buf0>} -> buf0 ready for next P1.

#define MM(MH, NH, AF, BB)                                                   \
    _Pragma("unroll") for (int p = 0; p < 2; ++p)                            \
        _Pragma("unroll") for (int ii = 0; ii < 4; ++ii)                     \
            _Pragma("unroll") for (int jj = 0; jj < 2; ++jj)                 \
                acc[(MH) * 4 + ii][(NH) * 2 + jj] =                          \
                    mfma16(AF[ii][p], BB[jj][p],                             \
                           acc[(MH) * 4 + ii][(NH) * 2 + jj]);

// mid-phase: barrier, lgkm drain, pin, raise prio
#define PH_A                                                                 \
    __builtin_amdgcn_s_barrier();                                            \
    asm volatile("s_waitcnt lgkmcnt(0)" ::: "memory");                       \
    __builtin_amdgcn_sched_barrier(0);                                       \
    __builtin_amdgcn_s_setprio(1);

// post-MFMA: drop prio, pin
#define PH_B                                                                 \
    __builtin_amdgcn_s_setprio(0);                                           \
    __builtin_amdgcn_sched_barrier(0);

// phase end barrier
#define PH_C                                                                 \
    __builtin_amdgcn_s_barrier();                                            \
    __builtin_amdgcn_sched_barrier(0);

// 4 phases of one K-tile in buffer BUF; S1..S4 staged at phase TOP.
#define KTILE(BUF, S1, S2, S3, S4)                                           \
    {                                                                        \
        s16x8 af[4][2], bl[2][2], bh[2][2];                                  \
        /* P1: 12 ds_reads, quadrant (0,0) */                                \
        _Pragma("unroll") for (int ii = 0; ii < 4; ++ii)                     \
            _Pragma("unroll") for (int p = 0; p < 2; ++p)                    \
                af[ii][p] = LDA(BUF, ii, p);                                 \
        _Pragma("unroll") for (int jj = 0; jj < 2; ++jj)                     \
            _Pragma("unroll") for (int p = 0; p < 2; ++p)                    \
                bl[jj][p] = LDB(BUF, jj, p);                                 \
        asm volatile("s_waitcnt lgkmcnt(8)" ::: "memory");                   \
        S1;                                                                  \
        PH_A;                                                                \
        MM(0, 0, af, bl);                                                    \
        PH_B;                                                                \
        PH_C;                                                                \
        /* P2: 4 ds_reads, quadrant (0,1) */                                 \
        _Pragma("unroll") for (int jj = 0; jj < 2; ++jj)                     \
            _Pragma("unroll") for (int p = 0; p < 2; ++p)                    \
                bh[jj][p] = LDB(BUF, 2 + jj, p);                             \
        S2;                                                                  \
        PH_A;                                                                \
        MM(0, 1, af, bh);                                                    \
        PH_B;                                                                \
        PH_C;                                                                \
        /* P3: 8 ds_reads, quadrant (1,1) */                                 \
        _Pragma("unroll") for (int ii = 0; ii < 4; ++ii)                     \
            _Pragma("unroll") for (int p = 0; p < 2; ++p)                    \
                af[ii][p] = LDA(BUF, 4 + ii, p);                             \
        S3;                                                                  \
        PH_A;                                                                \
        MM(1, 1, af, bh);                                                    \
        PH_B;                                                                \
        PH_C;                                                                \
        /* P4: quadrant (1,0); vmcnt AFTER the MFMA cluster */               \
        S4;                                                                  \
        PH_A;                                                                \
        MM(1, 0, af, bl);                                                    \
        PH_B;                                                                \
        asm volatile("s_waitcnt vmcnt(4)" ::: "memory");                     \
        PH_C;                                                                \
    }

// MODE 0: QKV scatter (Q pre-scaled, K -> [2][B,H,S,HD], V -> vt [B,H,HD,S])
// MODE 1: out f32 = acc + bias[col] + resid   MODE 2: out bf16 = gelu(acc+b)
template <int MODE>
__global__ __launch_bounds__(512, 2) void gemm256(
    const short* __restrict__ A, const short* __restrict__ Bt,
    const float* __restrict__ bias, const float* __restrict__ resid,
    float* __restrict__ outf, short* __restrict__ outb, short* __restrict__ vt,
    int M, int N, int K) {
    __shared__ __align__(16) short As[32768];   // 2 bufs x 2 halves x 8192
    __shared__ __align__(16) short Bs[32768];

    const int tid = threadIdx.x;
    const int wave = tid >> 6, lane = tid & 63;
    const int l16 = lane & 15, quad = lane >> 4;
    const int wm = wave >> 2, wn = wave & 3;    // 2 x 4 wave grid

    // XCD-chunked bijective swizzle (gridDim.x % 8 == 0), m-fastest order.
    const int nwg = gridDim.x;
    const int g = blockIdx.x;
    const int wgid = (g & 7) * (nwg >> 3) + (g >> 3);
    const int mtiles = M >> 8;
    const int m0 = (wgid % mtiles) << 8;
    const int n0 = (wgid / mtiles) << 8;

    // ---- read-side swizzled offsets (shorts)
    const int rc = l16 * 32 + ((quad * 8) ^ ((l16 >> 3) << 4));
    const int a_rd = wm * 8192 + rc;                    // + (i*2+p)*512
    const int b_rd = (wn >> 1) * 8192 + (wn & 1) * 4096 + rc;

    auto LDA = [&](int buf, int i, int p) {
        return *(const s16x8*)&As[buf * 16384 + a_rd + (i * 2 + p) * 512];
    };
    auto LDB = [&](int buf, int j, int p) {
        return *(const s16x8*)&Bs[buf * 16384 + b_rd + (j * 2 + p) * 512];
    };

    // ---- stage-side inverse swizzle: linear chunk s=tid*16 bytes holds (r,c)
    int r0, c0, r1, c1;
    {
        int s = tid * 16;
        int lin = s ^ (((s >> 9) & 1) << 5);
        r0 = ((lin >> 11) << 4) + ((lin >> 6) & 15);
        c0 = (((lin >> 10) & 1) << 5) + ((lin & 63) >> 1);
        s = (tid + 512) * 16;
        lin = s ^ (((s >> 9) & 1) << 5);
        r1 = ((lin >> 11) << 4) + ((lin >> 6) & 15);
        c1 = (((lin >> 10) & 1) << 5) + ((lin & 63) >> 1);
    }

    const short* gA = A + (size_t)m0 * K;
    const short* gB = Bt + (size_t)n0 * K;

    auto STAGE = [&](const short* gbase, int half, int kk, short* lds) {
        const short* s0 = gbase + (size_t)(half * 128 + r0) * K + kk + c0;
        const short* s1 = gbase + (size_t)(half * 128 + r1) * K + kk + c1;
        short* d0 = lds + half * 8192 + wave * 512;
        short* d1 = lds + half * 8192 + 4096 + wave * 512;
        __builtin_amdgcn_global_load_lds((g_void*)s0, (l_void*)d0, 16, 0, 0);
        __builtin_amdgcn_global_load_lds((g_void*)s1, (l_void*)d1, 16, 0, 0);
    };

    f32x4 acc[8][4] = {};

    // prologue: buf0 {B,A} (tile0), buf1 {B} (tile1); confirm buf0, keep
    // B<buf1> (4 loads) in flight -> steady-state invariant at loop entry.
    STAGE(gB, 0, 0, Bs);
    STAGE(gB, 1, 0, Bs);
    STAGE(gA, 0, 0, As);
    STAGE(gA, 1, 0, As);
    STAGE(gB, 0, 64, Bs + 16384);
    STAGE(gB, 1, 64, Bs + 16384);
    asm volatile("s_waitcnt vmcnt(4)" ::: "memory");   // buf0 complete
    __builtin_amdgcn_s_barrier();
    __builtin_amdgcn_sched_barrier(0);

    const int NI = K >> 7;                              // 2 K-tiles / iter
    for (int it = 0; it < NI; ++it) {
        const int kT1 = (2 * it + 1) * 64;              // tile T+1 (buf1 A)
        int kT2 = (2 * it + 2) * 64;                    // tile T+2 (buf0)
        if (kT2 > K - 64) kT2 = K - 64;                 // clamp (harmless dup)
        int kT3 = (2 * it + 3) * 64;                    // tile T+3 (buf1 B)
        if (kT3 > K - 64) kT3 = K - 64;

        KTILE(0,
              STAGE(gA, 0, kT1, As + 16384),            // P1: A buf1 h0
              STAGE(gA, 1, kT1, As + 16384),            // P2: A buf1 h1
              STAGE(gB, 0, kT2, Bs),                    // P3: B buf0 h0
              STAGE(gB, 1, kT2, Bs));                   // P4: B buf0 h1
        KTILE(1,
              STAGE(gA, 0, kT2, As),                    // P5: A buf0 h0
              STAGE(gA, 1, kT2, As),                    // P6: A buf0 h1
              STAGE(gB, 0, kT3, Bs + 16384),            // P7: B buf1 h0
              STAGE(gB, 1, kT3, Bs + 16384));           // P8: B buf1 h1
    }
    asm volatile("s_waitcnt vmcnt(0)" ::: "memory");    // drain trailing stages

    // ---- epilogue
#pragma unroll
    for (int i = 0; i < 8; ++i) {
#pragma unroll
        for (int j = 0; j < 4; ++j) {
            const int row = m0 + wm * 128 + i * 16 + quad * 4;   // + r
            const int col = n0 + wn * 64 + j * 16 + l16;
            const float bc = bias[col];
            float v[4];
#pragma unroll
            for (int r = 0; r < 4; ++r) v[r] = acc[i][j][r] + bc;

            if (MODE == 0) {
                const int sel = col >> 10, within = col & 1023;
                const int h = within >> 6, hd = within & 63;
                const size_t bidx = (size_t)row >> 11, sp = row & 2047;
                if (sel == 0) {
#pragma unroll
                    for (int r = 0; r < 4; ++r) v[r] *= 0.18033688011112042f;
                }
                if (sel < 2) {
#pragma unroll
                    for (int r = 0; r < 4; ++r)
                        outb[(size_t)sel * (8192ull * 1024) +
                             ((bidx * 16 + h) * 2048 + sp + r) * 64 + hd] = f2b(v[r]);
                } else {
                    short4 o4;
                    o4.x = f2b(v[0]); o4.y = f2b(v[1]);
                    o4.z = f2b(v[2]); o4.w = f2b(v[3]);
                    *(short4*)&vt[((bidx * 16 + h) * 64 + hd) * 2048 + sp] = o4;
                }
            } else if (MODE == 1) {
#pragma unroll
                for (int r = 0; r < 4; ++r) {
                    const size_t rr = (size_t)(row + r);
                    outf[rr * N + col] = v[r] + resid[rr * N + col];
                }
            } else {
#pragma unroll
                for (int r = 0; r < 4; ++r)
                    outb[(size_t)(row + r) * N + col] = f2b(fast_gelu(v[r]));
            }
        }
    }
}

#undef KTILE
#undef PH_A
#undef PH_B
#undef PH_C
#undef MM

// ---------------- causal flash attention v4: S^T formulation, no-max softmax,
// double-buffered K/V (one barrier/iter), XCD-affinity block mapping.
__global__ __launch_bounds__(256) void attn_kernel(
    const short* __restrict__ Q, const short* __restrict__ K,
    const short* __restrict__ Vt, short* __restrict__ O) {
    const int bid = blockIdx.x;
    const int xcd = bid & 7;
    const int sub = (bid >> 3) & 7;    // gq
    const int grp = bid >> 6;          // 0..7
    const int bh  = grp * 8 + xcd;     // bh % 8 == xcd
    const int h = bh & 15, b = bh >> 4;
    const int gq = sub;
    const int tid = threadIdx.x, wave = tid >> 6, lane = tid & 63;
    const int l16 = lane & 15, quad = lane >> 4;

    __shared__ __align__(16) short Ks[2][64 * 72];
    __shared__ __align__(16) short Vts[2][64 * 72];
    __shared__ __align__(16) short Ps[4][16 * 72];

    const size_t bhoff = (size_t)bh * (2048ull * 64);
    const int srow = tid >> 2;
    const int sseg = (tid & 3) * 16;

    const int qts[4] = {gq, 15 - gq, 16 + gq, 31 - gq};

    for (int pass = 0; pass < 4; ++pass) {
        const int qt = qts[pass];
        const int q0 = qt * 64;
        const int q_lane = q0 + wave * 16 + l16;

        const short* qrow = Q + bhoff + (size_t)q_lane * 64;
        s16x8 bq0 = *(const s16x8*)(qrow + quad * 8);
        s16x8 bq1 = *(const s16x8*)(qrow + 32 + quad * 8);

        f32x4 oacc[4] = {};
        float lsum = 0.0f;

        // prologue: load j=0 tile
        s16x8 k0, k1, v0, v1;
        {
            const short* kg = K + bhoff + (size_t)srow * 64 + sseg;
            k0 = *(const s16x8*)kg;
            k1 = *(const s16x8*)(kg + 8);
            const short* vg = Vt + bhoff + (size_t)srow * 2048 + sseg;
            v0 = *(const s16x8*)vg;
            v1 = *(const s16x8*)(vg + 8);
        }

        for (int j = 0; j <= qt; ++j) {
            const int buf = j & 1;
            *(s16x8*)&Ks[buf][srow * 72 + sseg]      = k0;
            *(s16x8*)&Ks[buf][srow * 72 + sseg + 8]  = k1;
            *(s16x8*)&Vts[buf][srow * 72 + sseg]     = v0;
            *(s16x8*)&Vts[buf][srow * 72 + sseg + 8] = v1;
            __syncthreads();

            if (j < qt) {
                const short* kg = K + bhoff + (size_t)((j + 1) * 64 + srow) * 64 + sseg;
                k0 = *(const s16x8*)kg;
                k1 = *(const s16x8*)(kg + 8);
                const short* vg = Vt + bhoff + (size_t)srow * 2048 + (j + 1) * 64 + sseg;
                v0 = *(const s16x8*)vg;
                v1 = *(const s16x8*)(vg + 8);
            }

            f32x4 st[4];
#pragma unroll
            for (int s = 0; s < 4; ++s) {
                s16x8 ak0 = *(const s16x8*)&Ks[buf][(s * 16 + l16) * 72 + quad * 8];
                s16x8 ak1 = *(const s16x8*)&Ks[buf][(s * 16 + l16) * 72 + 32 + quad * 8];
                f32x4 c = {};
                c = mfma16(ak0, bq0, c);
                c = mfma16(ak1, bq1, c);
                st[s] = c;
            }
            if (j == qt) {
#pragma unroll
                for (int s = 0; s < 4; ++s)
#pragma unroll
                    for (int r = 0; r < 4; ++r) {
                        const int t = j * 64 + s * 16 + quad * 4 + r;
                        if (t > q_lane) st[s][r] = -3000.0f;
                    }
            }
            float rs = 0.0f;
#pragma unroll
            for (int s = 0; s < 4; ++s) {
#pragma unroll
                for (int r = 0; r < 4; ++r) {
                    st[s][r] = exp2f(st[s][r]);
                    rs += st[s][r];
                }
                int2 pw;
                pw.x = pk2(st[s][0], st[s][1]);
                pw.y = pk2(st[s][2], st[s][3]);
                *(int2*)&Ps[wave][l16 * 72 + s * 16 + quad * 4] = pw;
            }
            rs += __shfl_xor(rs, 16);
            rs += __shfl_xor(rs, 32);
            lsum += rs;

            asm volatile("s_waitcnt lgkmcnt(0)" ::: "memory");
            s16x8 ap0 = *(const s16x8*)&Ps[wave][l16 * 72 + quad * 8];
            s16x8 ap1 = *(const s16x8*)&Ps[wave][l16 * 72 + 32 + quad * 8];

#pragma unroll
            for (int nt = 0; nt < 4; ++nt) {
                s16x8 bv0 = *(const s16x8*)&Vts[buf][(nt * 16 + l16) * 72 + quad * 8];
                s16x8 bv1 = *(const s16x8*)&Vts[buf][(nt * 16 + l16) * 72 + 32 + quad * 8];
                oacc[nt] = mfma16(ap0, bv0, oacc[nt]);
                oacc[nt] = mfma16(ap1, bv1, oacc[nt]);
            }
        }
        __syncthreads();

        float inv[4];
#pragma unroll
        for (int r = 0; r < 4; ++r)
            inv[r] = 1.0f / __shfl(lsum, quad * 4 + r, 64);
#pragma unroll
        for (int nt = 0; nt < 4; ++nt)
#pragma unroll
            for (int r = 0; r < 4; ++r) {
                const int row = q0 + wave * 16 + quad * 4 + r;
                O[((size_t)b * 2048 + row) * 1024 + h * 64 + nt * 16 + l16] =
                    f2b(oacc[nt][r] * inv[r]);
            }
    }
}

extern "C" void kernel_launch(void* const* d_in, const int* in_sizes, int n_in,
                              void* d_out, int out_size, void* d_ws, size_t ws_size,
                              hipStream_t stream) {
    const float* x     = (const float*)d_in[0];
    const float* Wq    = (const float*)d_in[1];
    const float* Wk    = (const float*)d_in[2];
    const float* Wv    = (const float*)d_in[3];
    const float* bq    = (const float*)d_in[4];
    const float* bk    = (const float*)d_in[5];
    const float* bv    = (const float*)d_in[6];
    const float* Wo    = (const float*)d_in[7];
    const float* bo    = (const float*)d_in[8];
    const float* W1    = (const float*)d_in[9];
    const float* b1    = (const float*)d_in[10];
    const float* W2    = (const float*)d_in[11];
    const float* b2    = (const float*)d_in[12];
    const float* gamma = (const float*)d_in[13];
    const float* beta  = (const float*)d_in[14];
    float* out = (float*)d_out;

    char* ws = (char*)d_ws;
    size_t off = 0;
    auto alloc = [&](size_t bytes) -> char* {
        char* p = ws + off;
        off += (bytes + 255) & ~(size_t)255;
        return p;
    };
    short* h1    = (short*)alloc(8192ull * 1024 * 2);
    short* btqkv = (short*)alloc(3072ull * 1024 * 2);
    short* btwo  = (short*)alloc(1024ull * 1024 * 2);
    short* btw1  = (short*)alloc(4096ull * 1024 * 2);
    short* btw2  = (short*)alloc(1024ull * 4096 * 2);
    float* bqkv  = (float*)alloc(3072ull * 4);
    short* qkv   = (short*)alloc(2ull * 8192 * 1024 * 2);   // Q,K only
    short* vt    = (short*)alloc(8192ull * 1024 * 2);       // V pre-transposed
    short* aout  = (short*)alloc(8192ull * 1024 * 2);
    float* x2    = (float*)alloc(8192ull * 1024 * 4);
    short* h2    = (short*)alloc(8192ull * 1024 * 2);
    short* m1    = (short*)alloc(8192ull * 4096 * 2);

    // weight prep
    transpose_bf16<<<dim3(2, 32, 16), 256, 0, stream>>>(Wq, btqkv, 1024, 64);
    transpose_bf16<<<dim3(2, 32, 16), 256, 0, stream>>>(Wk, btqkv + 1024ull * 1024, 1024, 64);
    transpose_bf16<<<dim3(2, 32, 16), 256, 0, stream>>>(Wv, btqkv + 2ull * 1024 * 1024, 1024, 64);
    transpose_bf16<<<dim3(32, 32, 1), 256, 0, stream>>>(Wo, btwo, 1024, 1024);
    transpose_bf16<<<dim3(128, 32, 1), 256, 0, stream>>>(W1, btw1, 1024, 4096);
    transpose_bf16<<<dim3(32, 128, 1), 256, 0, stream>>>(W2, btw2, 4096, 1024);
    concat_bias<<<12, 256, 0, stream>>>(bq, bk, bv, bqkv);

    // LN1
    ln_bf16<<<8192, 256, 0, stream>>>(x, gamma, beta, h1);
    // QKV projection: 256^2 v3 (32 m-tiles x 12 n-tiles)
    gemm256<0><<<384, 512, 0, stream>>>(
        h1, btqkv, bqkv, nullptr, nullptr, qkv, vt, 8192, 3072, 1024);
    // attention (XCD-affinity mapping)
    attn_kernel<<<512, 256, 0, stream>>>(
        qkv, qkv + 8192ull * 1024, vt, aout);
    // Wo + residual -> x2 (f32): narrow-N, 128^2 kernel
    gemm_bf16<1, 0><<<dim3(8, 64), 512, 0, stream>>>(
        aout, btwo, bo, x, x2, nullptr, nullptr, 8192, 1024, 1024);
    // LN2
    ln_bf16<<<8192, 256, 0, stream>>>(x2, gamma, beta, h2);
    // MLP1 + GELU: 256^2 v3 (32 x 16 = 512 blocks, 2/CU rounds)
    gemm256<2><<<512, 512, 0, stream>>>(
        h2, btw1, b1, nullptr, nullptr, m1, nullptr, 8192, 4096, 1024);
    // MLP2 + residual -> out (f32), narrow-N long-K: 128^2 M-band kernel
    gemm_bf16<1, 1><<<dim3(8, 64), 512, 0, stream>>>(
        m1, btw2, b2, x2, out, nullptr, nullptr, 8192, 1024, 4096);
}

// Round 4
// 523.137 us; speedup vs baseline: 1.0153x; 1.0076x over previous
//
#include <hip/hip_runtime.h>
#include <hip/hip_bf16.h>

typedef __bf16  bf16x8 __attribute__((ext_vector_type(8)));
typedef float   f32x4  __attribute__((ext_vector_type(4)));
typedef short   s16x8  __attribute__((ext_vector_type(8)));
typedef int     i32x4  __attribute__((ext_vector_type(4)));

typedef const __attribute__((address_space(1))) void g_void;
typedef __attribute__((address_space(3))) void l_void;

__device__ __forceinline__ short f2b(float x) {
    __hip_bfloat16 h = __float2bfloat16(x);
    return __builtin_bit_cast(short, h);
}

// pack two floats to bf16 pair in one int (lo | hi<<16)
__device__ __forceinline__ int pk2(float lo, float hi) {
    return (int)(unsigned short)f2b(lo) | ((int)f2b(hi) << 16);
}

// fast GELU: tanh form via hardware exp2. gelu(v) = v*t/(t+1),
// t = exp2(K1*(v + 0.044715 v^3)), K1 = 2*log2(e)*0.7978845608.
__device__ __forceinline__ float fast_gelu(float v) {
    const float a = fminf(2.3022082f * (v + 0.044715f * v * v * v), 126.0f);
    const float t = exp2f(a);
    return v * t / (t + 1.0f);
}

__device__ __forceinline__ f32x4 mfma16(s16x8 a, s16x8 b, f32x4 c) {
    return __builtin_amdgcn_mfma_f32_16x16x32_bf16(
        __builtin_bit_cast(bf16x8, a), __builtin_bit_cast(bf16x8, b), c, 0, 0, 0);
}

#define S16(x) __builtin_bit_cast(s16x8, x)

// ---------------- transpose + fp32 -> bf16 :  src [R,C] f32 -> dst [C,R] bf16
__global__ __launch_bounds__(256) void transpose_bf16(
    const float* __restrict__ src, short* __restrict__ dst, int R, int C) {
    __shared__ float tile[32][33];
    src += (size_t)blockIdx.z * R * C;
    dst += (size_t)blockIdx.z * R * C;
    const int c0 = blockIdx.x * 32, r0 = blockIdx.y * 32;
    const int tx = threadIdx.x & 31, ty = threadIdx.x >> 5;
#pragma unroll
    for (int i = 0; i < 32; i += 8)
        tile[ty + i][tx] = src[(size_t)(r0 + ty + i) * C + c0 + tx];
    __syncthreads();
#pragma unroll
    for (int i = 0; i < 32; i += 8)
        dst[(size_t)(c0 + ty + i) * R + r0 + tx] = f2b(tile[tx][ty + i]);
}

// ---------------- concat q/k/v bias into [3072] f32
__global__ __launch_bounds__(256) void concat_bias(
    const float* __restrict__ bq, const float* __restrict__ bk,
    const float* __restrict__ bv, float* __restrict__ o) {
    int i = blockIdx.x * 256 + threadIdx.x;
    if (i < 1024)      o[i] = bq[i];
    else if (i < 2048) o[i] = bk[i - 1024];
    else if (i < 3072) o[i] = bv[i - 2048];
}

// ---------------- LayerNorm (D=1024) f32 in -> bf16 out. 1 block/row, 256 thr
__global__ __launch_bounds__(256) void ln_bf16(
    const float* __restrict__ x, const float* __restrict__ gamma,
    const float* __restrict__ beta, short* __restrict__ out) {
    __shared__ float red[8];
    const int row = blockIdx.x, tid = threadIdx.x;
    const float4 v = *(const float4*)(x + (size_t)row * 1024 + tid * 4);
    float s = v.x + v.y + v.z + v.w;
    float q = v.x * v.x + v.y * v.y + v.z * v.z + v.w * v.w;
#pragma unroll
    for (int off = 32; off > 0; off >>= 1) {
        s += __shfl_xor(s, off);
        q += __shfl_xor(q, off);
    }
    if ((tid & 63) == 0) { red[(tid >> 6) * 2] = s; red[(tid >> 6) * 2 + 1] = q; }
    __syncthreads();
    s = red[0] + red[2] + red[4] + red[6];
    q = red[1] + red[3] + red[5] + red[7];
    const float mu = s * (1.0f / 1024.0f);
    const float var = q * (1.0f / 1024.0f) - mu * mu;
    const float rs = rsqrtf(var + 1e-5f);
    const float4 g  = *(const float4*)(gamma + tid * 4);
    const float4 bt = *(const float4*)(beta + tid * 4);
    short4 o;
    o.x = f2b((v.x - mu) * rs * g.x + bt.x);
    o.y = f2b((v.y - mu) * rs * g.y + bt.y);
    o.z = f2b((v.z - mu) * rs * g.z + bt.z);
    o.w = f2b((v.w - mu) * rs * g.w + bt.w);
    *(short4*)(out + (size_t)row * 1024 + tid * 4) = o;
}

// ---------------- bf16 MFMA GEMM (128x128, 2-barrier) for narrow-N GEMMs.
// MODE 1: f32 = acc+bias+resid  MODE 2: bf16 gelu(acc+b)
template <int MODE, int SWZ>
__global__ __launch_bounds__(512) void gemm_bf16(
    const short* __restrict__ A, const short* __restrict__ Bt,
    const float* __restrict__ bias, const float* __restrict__ resid,
    float* __restrict__ outf, short* __restrict__ outb, short* __restrict__ vt,
    int M, int N, int K) {
    __shared__ __align__(16) short As[2 * 128 * 32];
    __shared__ __align__(16) short Bs[2 * 128 * 32];

    const int tid = threadIdx.x;
    const int wave = tid >> 6, lane = tid & 63;
    const int l16 = lane & 15, quad = lane >> 4;
    const int wm = wave & 3, wn = wave >> 2;   // 4 row-strips x 2 col-strips
    const int gx = gridDim.x;
    const int g = blockIdx.y * gx + blockIdx.x;
    const int xcd = g & 7, s = g >> 3;
    int m0, n0;
    if (SWZ == 0) {                            // N-band (requires gx % 8 == 0)
        const int nband = gx >> 3;
        const int sm = s / nband;
        const int sn = s - sm * nband;
        m0 = sm * 128;
        n0 = (xcd * nband + sn) * 128;
    } else {                                   // M-band (requires gy % 8 == 0)
        const int mband = gridDim.y >> 3;
        const int sm = s / gx;
        m0 = (xcd * mband + sm) * 128;
        n0 = (s - sm * gx) * 128;
    }
    const int lrow = lane >> 2;        // 0..15
    const int lcol = (lane & 3) * 8;   // 16B chunk within a 32-elem panel row

    f32x4 acc[2][4] = {};

    for (int kk = 0; kk < K; kk += 64) {
#pragma unroll
        for (int p = 0; p < 2; ++p) {        // 32-K panel
            const int r = wave * 16 + lrow;  // 8 waves x 16 rows = 128
            const short* ga = A + (size_t)(m0 + r) * K + kk + p * 32 + lcol;
            short* la = &As[p * 4096 + wave * 512];
            __builtin_amdgcn_global_load_lds((g_void*)ga, (l_void*)la, 16, 0, 0);
            const short* gb = Bt + (size_t)(n0 + r) * K + kk + p * 32 + lcol;
            short* lb = &Bs[p * 4096 + wave * 512];
            __builtin_amdgcn_global_load_lds((g_void*)gb, (l_void*)lb, 16, 0, 0);
        }
        __syncthreads();
#pragma unroll
        for (int p = 0; p < 2; ++p) {
            s16x8 a[2], b[4];
#pragma unroll
            for (int t = 0; t < 2; ++t)
                a[t] = *(const s16x8*)&As[p * 4096 + (wm * 32 + t * 16 + l16) * 32 + quad * 8];
#pragma unroll
            for (int t = 0; t < 4; ++t)
                b[t] = *(const s16x8*)&Bs[p * 4096 + (wn * 64 + t * 16 + l16) * 32 + quad * 8];
#pragma unroll
            for (int mt = 0; mt < 2; ++mt)
#pragma unroll
                for (int nt = 0; nt < 4; ++nt)
                    acc[mt][nt] = mfma16(a[mt], b[nt], acc[mt][nt]);
        }
        __syncthreads();
    }

#pragma unroll
    for (int mt = 0; mt < 2; ++mt) {
#pragma unroll
        for (int nt = 0; nt < 4; ++nt) {
            const int row = m0 + wm * 32 + mt * 16 + quad * 4;   // + r
            const int col = n0 + wn * 64 + nt * 16 + l16;
            const float bc = bias[col];
            float v[4];
#pragma unroll
            for (int r = 0; r < 4; ++r) v[r] = acc[mt][nt][r] + bc;

            if (MODE == 1) {
#pragma unroll
                for (int r = 0; r < 4; ++r) {
                    const size_t rr = (size_t)(row + r);
                    outf[rr * N + col] = v[r] + resid[rr * N + col];
                }
            } else {
#pragma unroll
                for (int r = 0; r < 4; ++r)
                    outb[(size_t)(row + r) * N + col] = f2b(fast_gelu(v[r]));
            }
        }
    }
}

// ======================= 256x256 8-phase GEMM v4 =============================
// R3 slot schedule, but ALL waits hand-counted and ALL LDS reads inline-asm
// (opaque to the memory legalizer -> no compiler-inserted vmcnt/lgkm drains).
// Per phase: issue reads grouped by k-panel -> lgkmcnt(n_panel1) -> 8 MFMA of
// panel 0 (overlaps panel-1 read drain) -> lgkmcnt(0) -> 8 MFMA panel 1.
// Stage slots per K-tile (buf X current, Y=other): {A<Y>h0, A<Y>h1, B<X>h0,
// B<X>h1}; vmcnt(4) after P4/P8 MFMA cluster; steady state 4 loads in flight.
// Hazards (re-derived): each stage issues >=1 barrier after the overwritten
// half's last lgkm-confirmed read; vmcnt(4)@P4 confirms all of buf1 (staged
// 2.5-6 phases earlier) before P5 reads it, symmetric at P8.

#define DSR(dst, b, o)                                                       \
    asm volatile("ds_read_b128 %0, %1 offset:" #o : "=v"(dst) : "v"(b))

#define LGKM(n)                                                              \
    asm volatile("s_waitcnt lgkmcnt(" #n ")" ::: "memory");                  \
    __builtin_amdgcn_sched_barrier(0)

#define MM8(MH, NH, A0, A1, A2, A3, B0, B1)                                  \
    acc[(MH)*4+0][(NH)*2+0] = mfma16(S16(A0), S16(B0), acc[(MH)*4+0][(NH)*2+0]); \
    acc[(MH)*4+0][(NH)*2+1] = mfma16(S16(A0), S16(B1), acc[(MH)*4+0][(NH)*2+1]); \
    acc[(MH)*4+1][(NH)*2+0] = mfma16(S16(A1), S16(B0), acc[(MH)*4+1][(NH)*2+0]); \
    acc[(MH)*4+1][(NH)*2+1] = mfma16(S16(A1), S16(B1), acc[(MH)*4+1][(NH)*2+1]); \
    acc[(MH)*4+2][(NH)*2+0] = mfma16(S16(A2), S16(B0), acc[(MH)*4+2][(NH)*2+0]); \
    acc[(MH)*4+2][(NH)*2+1] = mfma16(S16(A2), S16(B1), acc[(MH)*4+2][(NH)*2+1]); \
    acc[(MH)*4+3][(NH)*2+0] = mfma16(S16(A3), S16(B0), acc[(MH)*4+3][(NH)*2+0]); \
    acc[(MH)*4+3][(NH)*2+1] = mfma16(S16(A3), S16(B1), acc[(MH)*4+3][(NH)*2+1])

// mid-phase: barrier, pin, raise prio (lgkm waits are counted, inside region)
#define PH_A                                                                 \
    __builtin_amdgcn_s_barrier();                                            \
    __builtin_amdgcn_sched_barrier(0);                                       \
    __builtin_amdgcn_s_setprio(1)

// post-MFMA: drop prio, pin
#define PH_B                                                                 \
    __builtin_amdgcn_s_setprio(0);                                           \
    __builtin_amdgcn_sched_barrier(0)

// phase end barrier
#define PH_C                                                                 \
    __builtin_amdgcn_s_barrier();                                            \
    __builtin_amdgcn_sched_barrier(0)

// 4 phases of one K-tile read through (AR,BR) LDS bases; S1..S4 staged at
// phase TOP (issue overlaps previous phase's MFMA drain).
#define KTILE(AR, BR, S1, S2, S3, S4)                                        \
    {                                                                        \
        i32x4 a0,a1,a2,a3,a4,a5,a6,a7, b0,b1,b2,b3, h0,h1,h2,h3;             \
        /* P1: quadrant (0,0); reads: A-half0, B-low (panel0 then panel1) */ \
        DSR(a0, AR, 0);    DSR(a1, AR, 2048); DSR(a2, AR, 4096); DSR(a3, AR, 6144); \
        DSR(b0, BR, 0);    DSR(b1, BR, 2048);                                \
        DSR(a4, AR, 1024); DSR(a5, AR, 3072); DSR(a6, AR, 5120); DSR(a7, AR, 7168); \
        DSR(b2, BR, 1024); DSR(b3, BR, 3072);                                \
        S1;                                                                  \
        PH_A;                                                                \
        LGKM(6); MM8(0, 0, a0, a1, a2, a3, b0, b1);                          \
        LGKM(0); MM8(0, 0, a4, a5, a6, a7, b2, b3);                          \
        PH_B; PH_C;                                                          \
        /* P2: quadrant (0,1); reads: B-high */                              \
        DSR(h0, BR, 4096); DSR(h1, BR, 6144);                                \
        DSR(h2, BR, 5120); DSR(h3, BR, 7168);                                \
        S2;                                                                  \
        PH_A;                                                                \
        LGKM(2); MM8(0, 1, a0, a1, a2, a3, h0, h1);                          \
        LGKM(0); MM8(0, 1, a4, a5, a6, a7, h2, h3);                          \
        PH_B; PH_C;                                                          \
        /* P3: quadrant (1,1); reads: A-half1 (reuse a regs) */              \
        DSR(a0, AR, 8192); DSR(a1, AR, 10240); DSR(a2, AR, 12288); DSR(a3, AR, 14336); \
        DSR(a4, AR, 9216); DSR(a5, AR, 11264); DSR(a6, AR, 13312); DSR(a7, AR, 15360); \
        S3;                                                                  \
        PH_A;                                                                \
        LGKM(4); MM8(1, 1, a0, a1, a2, a3, h0, h1);                          \
        LGKM(0); MM8(1, 1, a4, a5, a6, a7, h2, h3);                          \
        PH_B; PH_C;                                                          \
        /* P4: quadrant (1,0); no reads; vmcnt after MFMA cluster */         \
        S4;                                                                  \
        PH_A;                                                                \
        MM8(1, 0, a0, a1, a2, a3, b0, b1);                                   \
        MM8(1, 0, a4, a5, a6, a7, b2, b3);                                   \
        PH_B;                                                                \
        asm volatile("s_waitcnt vmcnt(4)" ::: "memory");                     \
        PH_C;                                                                \
    }

// MODE 0: QKV scatter (Q pre-scaled, K -> [2][B,H,S,HD], V -> vt [B,H,HD,S])
// MODE 1: out f32 = acc + bias[col] + resid   MODE 2: out bf16 = gelu(acc+b)
template <int MODE>
__global__ __launch_bounds__(512, 2) void gemm256(
    const short* __restrict__ A, const short* __restrict__ Bt,
    const float* __restrict__ bias, const float* __restrict__ resid,
    float* __restrict__ outf, short* __restrict__ outb, short* __restrict__ vt,
    int M, int N, int K) {
    __shared__ __align__(16) short As[32768];   // 2 bufs x 2 halves x 8192
    __shared__ __align__(16) short Bs[32768];

    const int tid = threadIdx.x;
    const int wave = tid >> 6, lane = tid & 63;
    const int l16 = lane & 15, quad = lane >> 4;
    const int wm = wave >> 2, wn = wave & 3;    // 2 x 4 wave grid

    // XCD-chunked bijective swizzle (gridDim.x % 8 == 0), m-fastest order.
    const int nwg = gridDim.x;
    const int g = blockIdx.x;
    const int wgid = (g & 7) * (nwg >> 3) + (g >> 3);
    const int mtiles = M >> 8;
    const int m0 = (wgid % mtiles) << 8;
    const int n0 = (wgid / mtiles) << 8;

    // ---- read-side swizzled offsets (shorts) -> 32-bit LDS byte addresses
    const int rc = l16 * 32 + ((quad * 8) ^ ((l16 >> 3) << 4));
    const int a_rd = wm * 8192 + rc;
    const int b_rd = (wn >> 1) * 8192 + (wn & 1) * 4096 + rc;

    const uint32_t asb = (uint32_t)(uintptr_t)(l_void*)&As[0];
    const uint32_t bsb = (uint32_t)(uintptr_t)(l_void*)&Bs[0];
    const uint32_t aRd0 = asb + 2u * (uint32_t)a_rd, aRd1 = aRd0 + 32768u;
    const uint32_t bRd0 = bsb + 2u * (uint32_t)b_rd, bRd1 = bRd0 + 32768u;

    // ---- stage-side inverse swizzle: linear chunk s=tid*16 bytes holds (r,c)
    int r0, c0, r1, c1;
    {
        int s = tid * 16;
        int lin = s ^ (((s >> 9) & 1) << 5);
        r0 = ((lin >> 11) << 4) + ((lin >> 6) & 15);
        c0 = (((lin >> 10) & 1) << 5) + ((lin & 63) >> 1);
        s = (tid + 512) * 16;
        lin = s ^ (((s >> 9) & 1) << 5);
        r1 = ((lin >> 11) << 4) + ((lin >> 6) & 15);
        c1 = (((lin >> 10) & 1) << 5) + ((lin & 63) >> 1);
    }

    const short* gA = A + (size_t)m0 * K;
    const short* gB = Bt + (size_t)n0 * K;

    auto STAGE = [&](const short* gbase, int half, int kk, short* lds) {
        const short* s0 = gbase + (size_t)(half * 128 + r0) * K + kk + c0;
        const short* s1 = gbase + (size_t)(half * 128 + r1) * K + kk + c1;
        short* d0 = lds + half * 8192 + wave * 512;
        short* d1 = lds + half * 8192 + 4096 + wave * 512;
        __builtin_amdgcn_global_load_lds((g_void*)s0, (l_void*)d0, 16, 0, 0);
        __builtin_amdgcn_global_load_lds((g_void*)s1, (l_void*)d1, 16, 0, 0);
    };

    f32x4 acc[8][4] = {};

    // prologue: buf0 {B,A} (tile0), buf1 {B} (tile1); confirm buf0, keep
    // B<buf1> (4 loads) in flight -> steady-state invariant at loop entry.
    STAGE(gB, 0, 0, Bs);
    STAGE(gB, 1, 0, Bs);
    STAGE(gA, 0, 0, As);
    STAGE(gA, 1, 0, As);
    STAGE(gB, 0, 64, Bs + 16384);
    STAGE(gB, 1, 64, Bs + 16384);
    asm volatile("s_waitcnt vmcnt(4)" ::: "memory");   // buf0 complete
    __builtin_amdgcn_s_barrier();
    __builtin_amdgcn_sched_barrier(0);

    const int NI = K >> 7;                              // 2 K-tiles / iter
    for (int it = 0; it < NI; ++it) {
        const int kT1 = (2 * it + 1) * 64;              // tile T+1 (buf1 A)
        int kT2 = (2 * it + 2) * 64;                    // tile T+2 (buf0)
        if (kT2 > K - 64) kT2 = K - 64;                 // clamp (harmless dup)
        int kT3 = (2 * it + 3) * 64;                    // tile T+3 (buf1 B)
        if (kT3 > K - 64) kT3 = K - 64;

        KTILE(aRd0, bRd0,
              STAGE(gA, 0, kT1, As + 16384),            // P1: A buf1 h0
              STAGE(gA, 1, kT1, As + 16384),            // P2: A buf1 h1
              STAGE(gB, 0, kT2, Bs),                    // P3: B buf0 h0
              STAGE(gB, 1, kT2, Bs));                   // P4: B buf0 h1
        KTILE(aRd1, bRd1,
              STAGE(gA, 0, kT2, As),                    // P5: A buf0 h0
              STAGE(gA, 1, kT2, As),                    // P6: A buf0 h1
              STAGE(gB, 0, kT3, Bs + 16384),            // P7: B buf1 h0
              STAGE(gB, 1, kT3, Bs + 16384));           // P8: B buf1 h1
    }
    asm volatile("s_waitcnt vmcnt(0)" ::: "memory");    // drain trailing stages

    // ---- epilogue
#pragma unroll
    for (int i = 0; i < 8; ++i) {
#pragma unroll
        for (int j = 0; j < 4; ++j) {
            const int row = m0 + wm * 128 + i * 16 + quad * 4;   // + r
            const int col = n0 + wn * 64 + j * 16 + l16;
            const float bc = bias[col];
            float v[4];
#pragma unroll
            for (int r = 0; r < 4; ++r) v[r] = acc[i][j][r] + bc;

            if (MODE == 0) {
                const int sel = col >> 10, within = col & 1023;
                const int h = within >> 6, hd = within & 63;
                const size_t bidx = (size_t)row >> 11, sp = row & 2047;
                if (sel == 0) {
                    // fold softmax scale (1/sqrt(64) * log2e) into Q
#pragma unroll
                    for (int r = 0; r < 4; ++r) v[r] *= 0.18033688011112042f;
                }
                if (sel < 2) {
#pragma unroll
                    for (int r = 0; r < 4; ++r)
                        outb[(size_t)sel * (8192ull * 1024) +
                             ((bidx * 16 + h) * 2048 + sp + r) * 64 + hd] = f2b(v[r]);
                } else {
                    short4 o4;
                    o4.x = f2b(v[0]); o4.y = f2b(v[1]);
                    o4.z = f2b(v[2]); o4.w = f2b(v[3]);
                    *(short4*)&vt[((bidx * 16 + h) * 64 + hd) * 2048 + sp] = o4;
                }
            } else if (MODE == 1) {
#pragma unroll
                for (int r = 0; r < 4; ++r) {
                    const size_t rr = (size_t)(row + r);
                    outf[rr * N + col] = v[r] + resid[rr * N + col];
                }
            } else {
#pragma unroll
                for (int r = 0; r < 4; ++r)
                    outb[(size_t)(row + r) * N + col] = f2b(fast_gelu(v[r]));
            }
        }
    }
}

#undef KTILE
#undef PH_A
#undef PH_B
#undef PH_C
#undef MM8
#undef LGKM
#undef DSR

// ---------------- causal flash attention v4: S^T formulation, no-max softmax,
// double-buffered K/V (one barrier/iter), XCD-affinity block mapping.
__global__ __launch_bounds__(256) void attn_kernel(
    const short* __restrict__ Q, const short* __restrict__ K,
    const short* __restrict__ Vt, short* __restrict__ O) {
    const int bid = blockIdx.x;
    const int xcd = bid & 7;
    const int sub = (bid >> 3) & 7;    // gq
    const int grp = bid >> 6;          // 0..7
    const int bh  = grp * 8 + xcd;     // bh % 8 == xcd
    const int h = bh & 15, b = bh >> 4;
    const int gq = sub;
    const int tid = threadIdx.x, wave = tid >> 6, lane = tid & 63;
    const int l16 = lane & 15, quad = lane >> 4;

    __shared__ __align__(16) short Ks[2][64 * 72];
    __shared__ __align__(16) short Vts[2][64 * 72];
    __shared__ __align__(16) short Ps[4][16 * 72];

    const size_t bhoff = (size_t)bh * (2048ull * 64);
    const int srow = tid >> 2;
    const int sseg = (tid & 3) * 16;

    const int qts[4] = {gq, 15 - gq, 16 + gq, 31 - gq};

    for (int pass = 0; pass < 4; ++pass) {
        const int qt = qts[pass];
        const int q0 = qt * 64;
        const int q_lane = q0 + wave * 16 + l16;

        const short* qrow = Q + bhoff + (size_t)q_lane * 64;
        s16x8 bq0 = *(const s16x8*)(qrow + quad * 8);
        s16x8 bq1 = *(const s16x8*)(qrow + 32 + quad * 8);

        f32x4 oacc[4] = {};
        float lsum = 0.0f;

        // prologue: load j=0 tile
        s16x8 k0, k1, v0, v1;
        {
            const short* kg = K + bhoff + (size_t)srow * 64 + sseg;
            k0 = *(const s16x8*)kg;
            k1 = *(const s16x8*)(kg + 8);
            const short* vg = Vt + bhoff + (size_t)srow * 2048 + sseg;
            v0 = *(const s16x8*)vg;
            v1 = *(const s16x8*)(vg + 8);
        }

        for (int j = 0; j <= qt; ++j) {
            const int buf = j & 1;
            *(s16x8*)&Ks[buf][srow * 72 + sseg]      = k0;
            *(s16x8*)&Ks[buf][srow * 72 + sseg + 8]  = k1;
            *(s16x8*)&Vts[buf][srow * 72 + sseg]     = v0;
            *(s16x8*)&Vts[buf][srow * 72 + sseg + 8] = v1;
            __syncthreads();

            if (j < qt) {
                const short* kg = K + bhoff + (size_t)((j + 1) * 64 + srow) * 64 + sseg;
                k0 = *(const s16x8*)kg;
                k1 = *(const s16x8*)(kg + 8);
                const short* vg = Vt + bhoff + (size_t)srow * 2048 + (j + 1) * 64 + sseg;
                v0 = *(const s16x8*)vg;
                v1 = *(const s16x8*)(vg + 8);
            }

            f32x4 st[4];
#pragma unroll
            for (int s = 0; s < 4; ++s) {
                s16x8 ak0 = *(const s16x8*)&Ks[buf][(s * 16 + l16) * 72 + quad * 8];
                s16x8 ak1 = *(const s16x8*)&Ks[buf][(s * 16 + l16) * 72 + 32 + quad * 8];
                f32x4 c = {};
                c = mfma16(ak0, bq0, c);
                c = mfma16(ak1, bq1, c);
                st[s] = c;
            }
            if (j == qt) {
#pragma unroll
                for (int s = 0; s < 4; ++s)
#pragma unroll
                    for (int r = 0; r < 4; ++r) {
                        const int t = j * 64 + s * 16 + quad * 4 + r;
                        if (t > q_lane) st[s][r] = -3000.0f;
                    }
            }
            float rs = 0.0f;
#pragma unroll
            for (int s = 0; s < 4; ++s) {
#pragma unroll
                for (int r = 0; r < 4; ++r) {
                    st[s][r] = exp2f(st[s][r]);
                    rs += st[s][r];
                }
                int2 pw;
                pw.x = pk2(st[s][0], st[s][1]);
                pw.y = pk2(st[s][2], st[s][3]);
                *(int2*)&Ps[wave][l16 * 72 + s * 16 + quad * 4] = pw;
            }
            rs += __shfl_xor(rs, 16);
            rs += __shfl_xor(rs, 32);
            lsum += rs;

            asm volatile("s_waitcnt lgkmcnt(0)" ::: "memory");
            s16x8 ap0 = *(const s16x8*)&Ps[wave][l16 * 72 + quad * 8];
            s16x8 ap1 = *(const s16x8*)&Ps[wave][l16 * 72 + 32 + quad * 8];

#pragma unroll
            for (int nt = 0; nt < 4; ++nt) {
                s16x8 bv0 = *(const s16x8*)&Vts[buf][(nt * 16 + l16) * 72 + quad * 8];
                s16x8 bv1 = *(const s16x8*)&Vts[buf][(nt * 16 + l16) * 72 + 32 + quad * 8];
                oacc[nt] = mfma16(ap0, bv0, oacc[nt]);
                oacc[nt] = mfma16(ap1, bv1, oacc[nt]);
            }
        }
        __syncthreads();

        float inv[4];
#pragma unroll
        for (int r = 0; r < 4; ++r)
            inv[r] = 1.0f / __shfl(lsum, quad * 4 + r, 64);
#pragma unroll
        for (int nt = 0; nt < 4; ++nt)
#pragma unroll
            for (int r = 0; r < 4; ++r) {
                const int row = q0 + wave * 16 + quad * 4 + r;
                O[((size_t)b * 2048 + row) * 1024 + h * 64 + nt * 16 + l16] =
                    f2b(oacc[nt][r] * inv[r]);
            }
    }
}

extern "C" void kernel_launch(void* const* d_in, const int* in_sizes, int n_in,
                              void* d_out, int out_size, void* d_ws, size_t ws_size,
                              hipStream_t stream) {
    const float* x     = (const float*)d_in[0];
    const float* Wq    = (const float*)d_in[1];
    const float* Wk    = (const float*)d_in[2];
    const float* Wv    = (const float*)d_in[3];
    const float* bq    = (const float*)d_in[4];
    const float* bk    = (const float*)d_in[5];
    const float* bv    = (const float*)d_in[6];
    const float* Wo    = (const float*)d_in[7];
    const float* bo    = (const float*)d_in[8];
    const float* W1    = (const float*)d_in[9];
    const float* b1    = (const float*)d_in[10];
    const float* W2    = (const float*)d_in[11];
    const float* b2    = (const float*)d_in[12];
    const float* gamma = (const float*)d_in[13];
    const float* beta  = (const float*)d_in[14];
    float* out = (float*)d_out;

    char* ws = (char*)d_ws;
    size_t off = 0;
    auto alloc = [&](size_t bytes) -> char* {
        char* p = ws + off;
        off += (bytes + 255) & ~(size_t)255;
        return p;
    };
    short* h1    = (short*)alloc(8192ull * 1024 * 2);
    short* btqkv = (short*)alloc(3072ull * 1024 * 2);
    short* btwo  = (short*)alloc(1024ull * 1024 * 2);
    short* btw1  = (short*)alloc(4096ull * 1024 * 2);
    short* btw2  = (short*)alloc(1024ull * 4096 * 2);
    float* bqkv  = (float*)alloc(3072ull * 4);
    short* qkv   = (short*)alloc(2ull * 8192 * 1024 * 2);   // Q,K only
    short* vt    = (short*)alloc(8192ull * 1024 * 2);       // V pre-transposed
    short* aout  = (short*)alloc(8192ull * 1024 * 2);
    float* x2    = (float*)alloc(8192ull * 1024 * 4);
    short* h2    = (short*)alloc(8192ull * 1024 * 2);
    short* m1    = (short*)alloc(8192ull * 4096 * 2);

    // weight prep
    transpose_bf16<<<dim3(2, 32, 16), 256, 0, stream>>>(Wq, btqkv, 1024, 64);
    transpose_bf16<<<dim3(2, 32, 16), 256, 0, stream>>>(Wk, btqkv + 1024ull * 1024, 1024, 64);
    transpose_bf16<<<dim3(2, 32, 16), 256, 0, stream>>>(Wv, btqkv + 2ull * 1024 * 1024, 1024, 64);
    transpose_bf16<<<dim3(32, 32, 1), 256, 0, stream>>>(Wo, btwo, 1024, 1024);
    transpose_bf16<<<dim3(128, 32, 1), 256, 0, stream>>>(W1, btw1, 1024, 4096);
    transpose_bf16<<<dim3(32, 128, 1), 256, 0, stream>>>(W2, btw2, 4096, 1024);
    concat_bias<<<12, 256, 0, stream>>>(bq, bk, bv, bqkv);

    // LN1
    ln_bf16<<<8192, 256, 0, stream>>>(x, gamma, beta, h1);
    // QKV projection: 256^2 v4 (32 m-tiles x 12 n-tiles)
    gemm256<0><<<384, 512, 0, stream>>>(
        h1, btqkv, bqkv, nullptr, nullptr, qkv, vt, 8192, 3072, 1024);
    // attention (XCD-affinity mapping)
    attn_kernel<<<512, 256, 0, stream>>>(
        qkv, qkv + 8192ull * 1024, vt, aout);
    // Wo + residual -> x2 (f32): narrow-N, 128^2 kernel
    gemm_bf16<1, 0><<<dim3(8, 64), 512, 0, stream>>>(
        aout, btwo, bo, x, x2, nullptr, nullptr, 8192, 1024, 1024);
    // LN2
    ln_bf16<<<8192, 256, 0, stream>>>(x2, gamma, beta, h2);
    // MLP1 + GELU: 256^2 v4 (32 x 16 = 512 blocks, 2/CU rounds)
    gemm256<2><<<512, 512, 0, stream>>>(
        h2, btw1, b1, nullptr, nullptr, m1, nullptr, 8192, 4096, 1024);
    // MLP2 + residual -> out (f32), narrow-N long-K: 128^2 M-band kernel
    gemm_bf16<1, 1><<<dim3(8, 64), 512, 0, stream>>>(
        m1, btw2, b2, x2, out, nullptr, nullptr, 8192, 1024, 4096);
}